// Round 13
// baseline (594.134 us; speedup 1.0000x reference)
//
#include <hip/hip_runtime.h>

// ConvSNN forward, T=16, B=128. One kernel per LAYER, t-loop inside, LIF state
// in REGISTERS. conv2/conv3/fc1 via MFMA bf16 with TRIPLE-split weights
// (hi+mid+lo ~= fp32 to ~2^-27 rel); activations are pooled spikes, exact bf16.
// B-fragments (t-invariant weights) live in REGISTERS for conv2/conv3/fc1.
// THIS ROUND: conv1 = round-11 structure (half-image LDS staging, 2thr/site,
// 4oc/thread) + weights HOISTED to registers once (was 28 b128 LDS reads per t).

typedef __attribute__((ext_vector_type(8))) short bf16x8;
typedef __attribute__((ext_vector_type(4))) float f32x4;

__device__ __forceinline__ unsigned short f2bf(float f) {
  unsigned int u = __float_as_uint(f);
  return (unsigned short)((u + 0x7fffu + ((u >> 16) & 1u)) >> 16);
}
__device__ __forceinline__ float bf2f(unsigned short h) {
  return __uint_as_float(((unsigned int)h) << 16);
}
__device__ __forceinline__ unsigned short split3(float wv, int sp) {
  unsigned short hi = f2bf(wv);
  float r1 = wv - bf2f(hi);
  unsigned short mid = f2bf(r1);
  if (sp == 0) return hi;
  if (sp == 1) return mid;
  return f2bf(r1 - bf2f(mid));
}
__device__ __forceinline__ float lif1(float inp, float vth, float& v, float& i) {
  float vd = fmaf(0.1f, i - v, v);
  float z = (vd > vth) ? 1.0f : 0.0f;
  v = (vd > vth) ? 0.0f : vd;
  i = fmaf(0.8f, i, inp);
  return z;
}
__device__ __forceinline__ f32x4 mfma16(bf16x8 a, bf16x8 b, f32x4 c) {
  return __builtin_amdgcn_mfma_f32_16x16x32_bf16(a, b, c, 0, 0, 0);
}

// ---------- one-time weight split+pack into B-fragment order ----------
// conv2 layout: [ocg 4][sp 3][dydx 9][g 4][ocl 16][j 8]  (ic = 8g+j); 55296
__global__ __launch_bounds__(256) void k_pack2(const float* __restrict__ wc2,
                                               unsigned short* __restrict__ wpk) {
  int idx = blockIdx.x * 256 + threadIdx.x;
  if (idx >= 55296) return;
  int j = idx & 7, ocl = (idx >> 3) & 15, g = (idx >> 7) & 3;
  int r = idx >> 9;                         // 0..107
  int dydx = r % 9; int q = r / 9;          // 0..11
  int sp = q % 3, ocg = q / 3;
  int oc = ocg * 16 + ocl, ic = g * 8 + j;
  wpk[idx] = split3(wc2[(oc * 32 + ic) * 9 + dydx], sp);
}
// conv3 layout: [ocg 8][ics 2][sp 3][dydx 9][g 4][ocl 16][j 8]; 442368
__global__ __launch_bounds__(256) void k_pack3(const float* __restrict__ wc3,
                                               unsigned short* __restrict__ wpk) {
  int idx = blockIdx.x * 256 + threadIdx.x;
  if (idx >= 442368) return;
  int j = idx & 7, ocl = (idx >> 3) & 15, g = (idx >> 7) & 3;
  int r = idx >> 9;
  int dydx = r % 9; int q = r / 9;
  int sp = q % 3; int q2 = q / 3;
  int ics = q2 & 1, ocg = q2 >> 1;
  int oc = ocg * 16 + ocl, ic = ics * 32 + g * 8 + j;
  wpk[idx] = split3(wc3[(oc * 64 + ic) * 9 + dydx], sp);
}

// ---------- conv1 (3->32) fp32, t-loop, state+WEIGHTS in regs -> z1bf[t] ----------
// grid 1024 = b(128) x h(2) x g(4: 8 oc); 256 thr = 128 sites x 2 sub(4 oc each).
__global__ __launch_bounds__(256, 2) void k_conv1(const float* __restrict__ x,
    const float* __restrict__ wc, unsigned short* __restrict__ z1bf)
{
  const int bid = blockIdx.x;
  const int g = bid & 3, h = (bid >> 2) & 1, b = bid >> 3;
  const int tid = threadIdx.x;
  __shared__ float xs[3][18][34];
  __shared__ __align__(16) float wl[8][28];
  for (int i = tid; i < 216; i += 256) wl[i / 27][i % 27] = wc[g * 216 + i];
  int ssrc[8];
#pragma unroll
  for (int k2 = 0; k2 < 8; ++k2) {
    int i = tid + k2 * 256;
    int v = -1;
    if (i < 1836) {
      int c = i / 612, rr = i % 612;
      int row = rr / 34, col = rr % 34;
      int gy = h * 16 + row - 1, gx = col - 1;
      if (gy >= 0 && gy < 32 && gx >= 0 && gx < 32) v = c * 1024 + gy * 32 + gx;
    }
    ssrc[k2] = v;
  }
  const int site = tid >> 1, sub = tid & 1;
  const int ph = site >> 4, pw = site & 15;
  const int py = h * 8 + ph;
  __syncthreads();                        // wl staged
  // hoist weights to registers ONCE (t-invariant): 4 oc x 28 floats
  float wreg[4][28];
#pragma unroll
  for (int jj = 0; jj < 4; ++jj) {
    const float4* wrow = (const float4*)&wl[sub * 4 + jj][0];
#pragma unroll
    for (int u = 0; u < 7; ++u) *(float4*)&wreg[jj][u * 4] = wrow[u];
  }
  float vst[4][4], ist[4][4];
#pragma unroll
  for (int jj = 0; jj < 4; ++jj)
#pragma unroll
    for (int r = 0; r < 4; ++r) { vst[jj][r] = 0.f; ist[jj][r] = 0.f; }

  for (int t = 0; t < 16; ++t) {
    __syncthreads();                      // prior-t readers of xs done
    const float* xt = x + (size_t)t * 393216 + b * 3072;
    float* xsf = &xs[0][0][0];
#pragma unroll
    for (int k2 = 0; k2 < 8; ++k2) {
      int i = tid + k2 * 256;
      if (i < 1836) xsf[i] = (ssrc[k2] >= 0) ? xt[ssrc[k2]] : 0.f;
    }
    __syncthreads();
    float p[3][4][4];
#pragma unroll
    for (int c = 0; c < 3; ++c)
#pragma unroll
      for (int r = 0; r < 4; ++r) {
        float2 q0 = *(const float2*)&xs[c][2 * ph + r][2 * pw];
        float2 q1 = *(const float2*)&xs[c][2 * ph + r][2 * pw + 2];
        p[c][r][0] = q0.x; p[c][r][1] = q0.y; p[c][r][2] = q1.x; p[c][r][3] = q1.y;
      }
    unsigned short zout[4];
#pragma unroll
    for (int jj = 0; jj < 4; ++jj) {
      float s00 = 0, s01 = 0, s10 = 0, s11 = 0;
#pragma unroll
      for (int c = 0; c < 3; ++c)
#pragma unroll
        for (int kh = 0; kh < 3; ++kh)
#pragma unroll
          for (int kw = 0; kw < 3; ++kw) {
            float wvv = wreg[jj][(c * 3 + kh) * 3 + kw];
            s00 = fmaf(p[c][kh][kw],     wvv, s00);
            s01 = fmaf(p[c][kh][kw+1],   wvv, s01);
            s10 = fmaf(p[c][kh+1][kw],   wvv, s10);
            s11 = fmaf(p[c][kh+1][kw+1], wvv, s11);
          }
      float z0 = lif1(s00, 0.25f, vst[jj][0], ist[jj][0]);
      float z1 = lif1(s01, 0.25f, vst[jj][1], ist[jj][1]);
      float z2 = lif1(s10, 0.25f, vst[jj][2], ist[jj][2]);
      float z3 = lif1(s11, 0.25f, vst[jj][3], ist[jj][3]);
      zout[jj] = f2bf(0.25f * (z0 + z1 + z2 + z3));
    }
    *(uint2*)&z1bf[(size_t)t * 1048576 + ((b * 16 + py) * 16 + pw) * 32 + g * 8 + sub * 4]
        = *(uint2*)zout;
  }
}

// ---------- conv2 (32->64) MFMA, B in REGS (27 frags), wave = 4 rows ----------
// grid 512 = ocg(4: 16 oc) x b(128); 256 thr = 4 waves.
__global__ __launch_bounds__(256, 2) void k_conv2(const unsigned short* __restrict__ z1bf,
    const unsigned short* __restrict__ wpk, unsigned short* __restrict__ z2bf)
{
  const int ocg = blockIdx.x & 3, b = blockIdx.x >> 2;
  const int tid = threadIdx.x;
  __shared__ __align__(16) unsigned short img[18][18][40];
  __shared__ __align__(16) unsigned short zpl[4][4][16][18];
  const int w = tid >> 6, l = tid & 63;
  const int lg = l >> 4, ll = l & 15;
  const int ry = ll >> 3, xi = ll & 7;
  bf16x8 bw[3][9];
  {
    const unsigned short* wp = wpk + ocg * 13824;
#pragma unroll
    for (int sp = 0; sp < 3; ++sp)
#pragma unroll
      for (int s9 = 0; s9 < 9; ++s9)
        bw[sp][s9] = *(const bf16x8*)(wp + ((sp * 9 + s9) * 4 + lg) * 128 + ll * 8);
  }
  int csrc[7];
#pragma unroll
  for (int k2 = 0; k2 < 7; ++k2) {
    int e = tid + k2 * 256;
    int v = -1;
    if (e < 1620) {
      int s = e / 5, u = e % 5;
      int row = s / 18, col = s % 18;
      int gy = row - 1, gx = col - 1;
      if (u < 4 && gy >= 0 && gy < 16 && gx >= 0 && gx < 16)
        v = ((b * 16 + gy) * 16 + gx) * 32 + u * 8;
    }
    csrc[k2] = v;
  }
  float vst[2][2][4], ist[2][2][4];
#pragma unroll
  for (int rp = 0; rp < 2; ++rp)
#pragma unroll
    for (int ch = 0; ch < 2; ++ch)
#pragma unroll
      for (int r = 0; r < 4; ++r) { vst[rp][ch][r] = 0.f; ist[rp][ch][r] = 0.f; }

  for (int t = 0; t < 16; ++t) {
    __syncthreads();
    {
      const unsigned short* zt = z1bf + (size_t)t * 1048576;
      uint4* imgu4 = (uint4*)&img[0][0][0];
#pragma unroll
      for (int k2 = 0; k2 < 7; ++k2) {
        int e = tid + k2 * 256;
        if (e < 1620) {
          uint4 val = {0, 0, 0, 0};
          if (csrc[k2] >= 0) val = *(const uint4*)(zt + csrc[k2]);
          imgu4[e] = val;
        }
      }
    }
    __syncthreads();
    f32x4 acc[2][2] = {};
#pragma unroll
    for (int s9 = 0; s9 < 9; ++s9) {
      const int dy = s9 / 3, dx = s9 % 3;
      bf16x8 a[2][2];
#pragma unroll
      for (int rp = 0; rp < 2; ++rp)
#pragma unroll
        for (int ch = 0; ch < 2; ++ch)
          a[rp][ch] = *(const bf16x8*)&img[4 * w + 2 * rp + ry + dy][ch * 8 + xi + dx][8 * lg];
#pragma unroll
      for (int sp = 0; sp < 3; ++sp)
#pragma unroll
        for (int rp = 0; rp < 2; ++rp)
#pragma unroll
          for (int ch = 0; ch < 2; ++ch)
            acc[rp][ch] = mfma16(a[rp][ch], bw[sp][s9], acc[rp][ch]);
    }
#pragma unroll
    for (int rp = 0; rp < 2; ++rp)
#pragma unroll
      for (int ch = 0; ch < 2; ++ch)
#pragma unroll
        for (int r = 0; r < 4; ++r) {
          int m = 4 * lg + r;
          float z = lif1(acc[rp][ch][r], 0.2f, vst[rp][ch][r], ist[rp][ch][r]);
          zpl[w][2 * rp + (m >> 3)][ch * 8 + (m & 7)][ll] = f2bf(z);
        }
#pragma unroll
    for (int pp = 0; pp < 4; ++pp) {
      int prow = lg >> 1, pcol = (lg & 1) * 4 + pp;
      float zs = bf2f(zpl[w][2*prow][2*pcol][ll])   + bf2f(zpl[w][2*prow][2*pcol+1][ll]) +
                 bf2f(zpl[w][2*prow+1][2*pcol][ll]) + bf2f(zpl[w][2*prow+1][2*pcol+1][ll]);
      z2bf[(size_t)t * 524288 + ((b * 8 + w * 2 + prow) * 8 + pcol) * 64 + ocg * 16 + ll]
          = f2bf(0.25f * zs);
    }
  }
}

// ---------- conv3 (64->128) MFMA full-K, B in REGS (54 frags) -> z3t[t] ----------
// grid 1024 = ocg(8: 16 oc) x b(128); 256 thr = 4 waves (row-pairs).
__global__ __launch_bounds__(256, 2) void k_conv3(const unsigned short* __restrict__ z2bf,
    const unsigned short* __restrict__ wpk, unsigned short* __restrict__ z3t)
{
  const int bid = blockIdx.x;
  const int ocg = bid & 7, b = bid >> 3;
  const int tid = threadIdx.x;
  __shared__ __align__(16) unsigned short img[10][12][72];
  __shared__ __align__(16) unsigned short zpl[4][16][18];
  const int w = tid >> 6, l = tid & 63;
  const int lg = l >> 4, ll = l & 15;
  const int ry = ll >> 3, xi = ll & 7;
  bf16x8 bw[2][3][9];
  {
    const unsigned short* wp = wpk + ocg * 27648;
#pragma unroll
    for (int ics = 0; ics < 2; ++ics)
#pragma unroll
      for (int sp = 0; sp < 3; ++sp)
#pragma unroll
        for (int s9 = 0; s9 < 9; ++s9)
          bw[ics][sp][s9] = *(const bf16x8*)(wp + ics * 13824 +
                                             ((sp * 9 + s9) * 4 + lg) * 128 + ll * 8);
  }
  int csrc[5];
#pragma unroll
  for (int k2 = 0; k2 < 5; ++k2) {
    int e = tid + k2 * 256;
    int v = -1;
    if (e < 1080) {
      int s = e / 9, u = e % 9;
      int row = s / 12, col = s % 12;
      int gy = row - 1, gx = col - 1;
      if (u < 8 && gy >= 0 && gy < 8 && gx >= 0 && gx < 8)
        v = ((b * 8 + gy) * 8 + gx) * 64 + u * 8;
    }
    csrc[k2] = v;
  }
  float vst[4], ist[4];
#pragma unroll
  for (int r = 0; r < 4; ++r) { vst[r] = 0.f; ist[r] = 0.f; }

  for (int t = 0; t < 16; ++t) {
    __syncthreads();
    {
      const unsigned short* zt = z2bf + (size_t)t * 524288;
      uint4* imgu4 = (uint4*)&img[0][0][0];
#pragma unroll
      for (int k2 = 0; k2 < 5; ++k2) {
        int e = tid + k2 * 256;
        if (e < 1080) {
          uint4 val = {0, 0, 0, 0};
          if (csrc[k2] >= 0) val = *(const uint4*)(zt + csrc[k2]);
          imgu4[e] = val;
        }
      }
    }
    __syncthreads();
    f32x4 acc = {};
#pragma unroll
    for (int ics = 0; ics < 2; ++ics)
#pragma unroll
      for (int s9 = 0; s9 < 9; ++s9) {
        const int dy = s9 / 3, dx = s9 % 3;
        bf16x8 a = *(const bf16x8*)&img[2 * w + ry + dy][xi + dx][ics * 32 + 8 * lg];
#pragma unroll
        for (int sp = 0; sp < 3; ++sp)
          acc = mfma16(a, bw[ics][sp][s9], acc);
      }
#pragma unroll
    for (int r = 0; r < 4; ++r) {
      int px = 4 * lg + r;
      float z = lif1(acc[r], 0.1f, vst[r], ist[r]);
      zpl[w][px][ll] = f2bf(z);
    }
    float zsum = bf2f(zpl[w][2*lg][ll])   + bf2f(zpl[w][2*lg+1][ll]) +
                 bf2f(zpl[w][8+2*lg][ll]) + bf2f(zpl[w][9+2*lg][ll]);
    z3t[(size_t)t * 262144 + b * 2048 + (ocg * 16 + ll) * 16 + w * 4 + lg]
        = f2bf(0.25f * zsum);
  }
}

// ---------- fc1 (2048->1024) MFMA, K-split 8, B in REGS (24 frags) ----------
// grid 1024 = kb8 x nb64(16 n) x bb2; 256 thr = 4 waves (bt). LDS = 32 KB slab only.
__global__ __launch_bounds__(256) void k_fc1(const unsigned short* __restrict__ z3t,
    const float* __restrict__ wf1, float* __restrict__ P1)
{
  const int bid = blockIdx.x;
  const int kb = bid & 7, nb = (bid >> 3) & 63, bb = bid >> 9;
  const int tid = threadIdx.x;
  __shared__ __align__(16) unsigned short slab[16384];  // wl3 staging first, then A-slab
  for (int i = tid; i < 4096; i += 256) {
    int n = i >> 8, k = i & 255;
    float wv = wf1[(size_t)(nb * 16 + n) * 2048 + kb * 256 + k];
    unsigned short hi = f2bf(wv);
    float r1 = wv - bf2f(hi);
    unsigned short mid = f2bf(r1);
    unsigned short lo = f2bf(r1 - bf2f(mid));
    int off = ((k >> 5) * 4 + ((k >> 3) & 3)) * 128 + n * 8 + (k & 7);
    slab[off] = hi; slab[4096 + off] = mid; slab[8192 + off] = lo;
  }
  __syncthreads();
  const int w = tid >> 6, l = tid & 63;
  const int lg = l >> 4, ll = l & 15;
  bf16x8 bwf[8][3];
#pragma unroll
  for (int ks = 0; ks < 8; ++ks)
#pragma unroll
    for (int sp = 0; sp < 3; ++sp)
      bwf[ks][sp] = *(const bf16x8*)&slab[sp * 4096 + (ks * 4 + lg) * 128 + ll * 8];
  const int arow = w * 16 + ll;
  const int bo = bb * 64 + w * 16;

  for (int t = 0; t < 16; ++t) {
    __syncthreads();                      // prior readers of slab done
    for (int gidx = tid; gidx < 2048; gidx += 256) {
      int row = gidx >> 5, gc = gidx & 31;
      const uint4* s = (const uint4*)(z3t + (size_t)t * 262144 +
                                      ((bb * 64 + row) * 2048 + kb * 256 + gc * 8));
      ((uint4*)slab)[row * 32 + (gc ^ (row & 7))] = *s;
    }
    __syncthreads();
    f32x4 acc = {};
#pragma unroll
    for (int ks = 0; ks < 8; ++ks) {
      bf16x8 a = *(const bf16x8*)&slab[(arow * 32 + ((ks * 4 + lg) ^ (arow & 7))) * 8];
#pragma unroll
      for (int sp = 0; sp < 3; ++sp)
        acc = mfma16(a, bwf[ks][sp], acc);
    }
    float* Pt = P1 + (size_t)t * 1048576 + (size_t)kb * 131072;
#pragma unroll
    for (int r = 0; r < 4; ++r)
      Pt[(bo + 4 * lg + r) * 1024 + nb * 16 + ll] = acc[r];
  }
}

// ---------- fc1 reduce + LIF(0.1), t-loop, state in regs -> z4bf[t][b][n] ----------
__global__ __launch_bounds__(256) void k_fc1b(const float* __restrict__ P1,
    unsigned short* __restrict__ z4bf)
{
  const int site = blockIdx.x * 256 + threadIdx.x;   // 131072 = b*1024+n
  float v = 0.f, ii = 0.f;
  for (int t = 0; t < 16; ++t) {
    const float* p = P1 + (size_t)t * 1048576 + site;
    float a = 0.f;
#pragma unroll
    for (int kb = 0; kb < 8; ++kb) a += p[(size_t)kb * 131072];
    float z = lif1(a, 0.1f, v, ii);
    z4bf[(size_t)t * 131072 + site] = f2bf(z);
  }
}

// ---------- out layer (1024->10) + LI + running max, t-loop, state in regs ----------
__global__ __launch_bounds__(256) void k_out(const unsigned short* __restrict__ z4bf,
    const float* __restrict__ wo, float* __restrict__ out)
{
  const int w = threadIdx.x >> 6, l = threadIdx.x & 63;
  const int b = blockIdx.x * 4 + w;
  float vo[10], io[10], om[10];
#pragma unroll
  for (int o = 0; o < 10; ++o) { vo[o] = 0.f; io[o] = 0.f; om[o] = 0.f; }
  for (int t = 0; t < 16; ++t) {
    float dot[10];
#pragma unroll
    for (int o = 0; o < 10; ++o) dot[o] = 0.f;
    for (int c = 0; c < 16; ++c) {
      const int n = c * 64 + l;
      float z = bf2f(z4bf[(size_t)t * 131072 + b * 1024 + n]);
#pragma unroll
      for (int o = 0; o < 10; ++o) dot[o] = fmaf(z, wo[o * 1024 + n], dot[o]);
    }
#pragma unroll
    for (int o = 0; o < 10; ++o)
#pragma unroll
      for (int d = 32; d > 0; d >>= 1) dot[o] += __shfl_down(dot[o], d);
    if (l == 0) {
#pragma unroll
      for (int o = 0; o < 10; ++o) {
        float vn = fmaf(0.1f, io[o] - vo[o], vo[o]);
        io[o] = fmaf(0.8f, io[o], dot[o]);
        vo[o] = vn;
        om[o] = (t == 0) ? vn : fmaxf(om[o], vn);
      }
    }
  }
  if (l == 0) {
#pragma unroll
    for (int o = 0; o < 10; ++o) out[b * 10 + o] = om[o];
  }
}

extern "C" void kernel_launch(void* const* d_in, const int* in_sizes, int n_in,
                              void* d_out, int out_size, void* d_ws, size_t ws_size,
                              hipStream_t stream)
{
  const float* x   = (const float*)d_in[0];   // (16,128,3,32,32)
  const float* wc1 = (const float*)d_in[1];   // (32,3,3,3)
  const float* wc2 = (const float*)d_in[2];   // (64,32,3,3)
  const float* wc3 = (const float*)d_in[3];   // (128,64,3,3)
  const float* wf1 = (const float*)d_in[4];   // (1024,2048)
  const float* wo  = (const float*)d_in[5];   // (10,1024)
  float* out = (float*)d_out;                 // (128,10)
  char* ws = (char*)d_ws;

  unsigned short* z1bf = (unsigned short*)(ws + 0);          // [16][128,16,16,32]
  unsigned short* z2bf = (unsigned short*)(ws + 33554432);   // [16][128,8,8,64]
  unsigned short* z3t  = (unsigned short*)(ws + 50331648);   // [16][128,2048]
  unsigned short* z4bf = (unsigned short*)(ws + 58720256);   // [16][128,1024]
  float* P1            = (float*)(ws + 62914560);            // [16][8][131072]
  unsigned short* wc2pk = (unsigned short*)(ws + 130023424);
  unsigned short* wc3pk = (unsigned short*)(ws + 130134016);

  k_pack2<<<216, 256, 0, stream>>>(wc2, wc2pk);
  k_pack3<<<1728, 256, 0, stream>>>(wc3, wc3pk);

  k_conv1<<<1024, 256, 0, stream>>>(x, wc1, z1bf);
  k_conv2<<<512, 256, 0, stream>>>(z1bf, wc2pk, z2bf);
  k_conv3<<<1024, 256, 0, stream>>>(z2bf, wc3pk, z3t);
  k_fc1 <<<1024, 256, 0, stream>>>(z3t, wf1, P1);
  k_fc1b<<<512, 256, 0, stream>>>(P1, z4bf);
  k_out <<<32, 256, 0, stream>>>(z4bf, wo, out);
}

// Round 14
// 388.339 us; speedup vs baseline: 1.5299x; 1.5299x over previous
//
#include <hip/hip_runtime.h>

// ConvSNN forward, T=16, B=128. One kernel per LAYER, t-loop inside, LIF state
// in REGISTERS. conv2/conv3/fc1 via MFMA bf16 with TRIPLE-split weights
// (hi+mid+lo ~= fp32 to ~2^-27 rel); activations are pooled spikes, exact bf16.
// B-fragments (t-invariant weights) live in REGISTERS for conv2/conv3/fc1.
// THIS ROUND: conv1 reverted to round-11 structure (known-good 105us; r12/r13
// variants over-fetched/spilled) + T14 async-STAGE split: next-t staging values
// prefetched into regs so global-load latency hides under compute.

typedef __attribute__((ext_vector_type(8))) short bf16x8;
typedef __attribute__((ext_vector_type(4))) float f32x4;

__device__ __forceinline__ unsigned short f2bf(float f) {
  unsigned int u = __float_as_uint(f);
  return (unsigned short)((u + 0x7fffu + ((u >> 16) & 1u)) >> 16);
}
__device__ __forceinline__ float bf2f(unsigned short h) {
  return __uint_as_float(((unsigned int)h) << 16);
}
__device__ __forceinline__ unsigned short split3(float wv, int sp) {
  unsigned short hi = f2bf(wv);
  float r1 = wv - bf2f(hi);
  unsigned short mid = f2bf(r1);
  if (sp == 0) return hi;
  if (sp == 1) return mid;
  return f2bf(r1 - bf2f(mid));
}
__device__ __forceinline__ float lif1(float inp, float vth, float& v, float& i) {
  float vd = fmaf(0.1f, i - v, v);
  float z = (vd > vth) ? 1.0f : 0.0f;
  v = (vd > vth) ? 0.0f : vd;
  i = fmaf(0.8f, i, inp);
  return z;
}
__device__ __forceinline__ f32x4 mfma16(bf16x8 a, bf16x8 b, f32x4 c) {
  return __builtin_amdgcn_mfma_f32_16x16x32_bf16(a, b, c, 0, 0, 0);
}

// ---------- one-time weight split+pack into B-fragment order ----------
// conv2 layout: [ocg 4][sp 3][dydx 9][g 4][ocl 16][j 8]  (ic = 8g+j); 55296
__global__ __launch_bounds__(256) void k_pack2(const float* __restrict__ wc2,
                                               unsigned short* __restrict__ wpk) {
  int idx = blockIdx.x * 256 + threadIdx.x;
  if (idx >= 55296) return;
  int j = idx & 7, ocl = (idx >> 3) & 15, g = (idx >> 7) & 3;
  int r = idx >> 9;                         // 0..107
  int dydx = r % 9; int q = r / 9;          // 0..11
  int sp = q % 3, ocg = q / 3;
  int oc = ocg * 16 + ocl, ic = g * 8 + j;
  wpk[idx] = split3(wc2[(oc * 32 + ic) * 9 + dydx], sp);
}
// conv3 layout: [ocg 8][ics 2][sp 3][dydx 9][g 4][ocl 16][j 8]; 442368
__global__ __launch_bounds__(256) void k_pack3(const float* __restrict__ wc3,
                                               unsigned short* __restrict__ wpk) {
  int idx = blockIdx.x * 256 + threadIdx.x;
  if (idx >= 442368) return;
  int j = idx & 7, ocl = (idx >> 3) & 15, g = (idx >> 7) & 3;
  int r = idx >> 9;
  int dydx = r % 9; int q = r / 9;
  int sp = q % 3; int q2 = q / 3;
  int ics = q2 & 1, ocg = q2 >> 1;
  int oc = ocg * 16 + ocl, ic = ics * 32 + g * 8 + j;
  wpk[idx] = split3(wc3[(oc * 64 + ic) * 9 + dydx], sp);
}

// ---------- conv1 (3->32) fp32, t-loop, state in regs -> z1bf[t] (B,16,16,32) ----------
// grid 1024 = b(128) x h(2) x g(4: 8 oc); 256 thr = 128 sites x 2 sub(4 oc each).
// Round-11 structure + T14 prefetch: staging values for t+1 loaded into regs
// during compute of t; only ds_writes sit between the barriers.
__global__ __launch_bounds__(256) void k_conv1(const float* __restrict__ x,
    const float* __restrict__ wc, unsigned short* __restrict__ z1bf)
{
  const int bid = blockIdx.x;
  const int g = bid & 3, h = (bid >> 2) & 1, b = bid >> 3;
  const int tid = threadIdx.x;
  __shared__ float xs[3][18][34];
  __shared__ __align__(16) float wl[8][28];    // rows padded 27->28
  for (int i = tid; i < 216; i += 256) wl[i / 27][i % 27] = wc[g * 216 + i];
  int ssrc[8];
#pragma unroll
  for (int k2 = 0; k2 < 8; ++k2) {
    int i = tid + k2 * 256;
    int v = -1;
    if (i < 1836) {
      int c = i / 612, rr = i % 612;
      int row = rr / 34, col = rr % 34;
      int gy = h * 16 + row - 1, gx = col - 1;
      if (gy >= 0 && gy < 32 && gx >= 0 && gx < 32) v = c * 1024 + gy * 32 + gx;
    }
    ssrc[k2] = v;
  }
  const int site = tid >> 1, sub = tid & 1;
  const int ph = site >> 4, pw = site & 15;
  const int py = h * 8 + ph;
  float vst[4][4], ist[4][4];
#pragma unroll
  for (int jj = 0; jj < 4; ++jj)
#pragma unroll
    for (int r = 0; r < 4; ++r) { vst[jj][r] = 0.f; ist[jj][r] = 0.f; }

  // prefetch t=0 staging values into regs
  float vals[8];
  {
    const float* xt0 = x + b * 3072;
#pragma unroll
    for (int k2 = 0; k2 < 8; ++k2)
      vals[k2] = (ssrc[k2] >= 0) ? xt0[ssrc[k2]] : 0.f;
  }

  for (int t = 0; t < 16; ++t) {
    __syncthreads();                      // prior-t readers of xs done (covers wl at t=0)
    float* xsf = &xs[0][0][0];
#pragma unroll
    for (int k2 = 0; k2 < 8; ++k2) {
      int i = tid + k2 * 256;
      if (i < 1836) xsf[i] = vals[k2];
    }
    if (t < 15) {                         // issue t+1 loads; latency hides under compute
      const float* xt = x + (size_t)(t + 1) * 393216 + b * 3072;
#pragma unroll
      for (int k2 = 0; k2 < 8; ++k2)
        vals[k2] = (ssrc[k2] >= 0) ? xt[ssrc[k2]] : 0.f;
    }
    __syncthreads();
    float p[3][4][4];
#pragma unroll
    for (int c = 0; c < 3; ++c)
#pragma unroll
      for (int r = 0; r < 4; ++r) {
        float2 q0 = *(const float2*)&xs[c][2 * ph + r][2 * pw];
        float2 q1 = *(const float2*)&xs[c][2 * ph + r][2 * pw + 2];
        p[c][r][0] = q0.x; p[c][r][1] = q0.y; p[c][r][2] = q1.x; p[c][r][3] = q1.y;
      }
    unsigned short zout[4];
#pragma unroll
    for (int jj = 0; jj < 4; ++jj) {
      float wreg[28];
      const float4* wrow = (const float4*)&wl[sub * 4 + jj][0];
#pragma unroll
      for (int u = 0; u < 7; ++u) *(float4*)&wreg[u * 4] = wrow[u];
      float s00 = 0, s01 = 0, s10 = 0, s11 = 0;
#pragma unroll
      for (int c = 0; c < 3; ++c)
#pragma unroll
        for (int kh = 0; kh < 3; ++kh)
#pragma unroll
          for (int kw = 0; kw < 3; ++kw) {
            float wvv = wreg[(c * 3 + kh) * 3 + kw];
            s00 = fmaf(p[c][kh][kw],     wvv, s00);
            s01 = fmaf(p[c][kh][kw+1],   wvv, s01);
            s10 = fmaf(p[c][kh+1][kw],   wvv, s10);
            s11 = fmaf(p[c][kh+1][kw+1], wvv, s11);
          }
      float z0 = lif1(s00, 0.25f, vst[jj][0], ist[jj][0]);
      float z1 = lif1(s01, 0.25f, vst[jj][1], ist[jj][1]);
      float z2 = lif1(s10, 0.25f, vst[jj][2], ist[jj][2]);
      float z3 = lif1(s11, 0.25f, vst[jj][3], ist[jj][3]);
      zout[jj] = f2bf(0.25f * (z0 + z1 + z2 + z3));
    }
    *(uint2*)&z1bf[(size_t)t * 1048576 + ((b * 16 + py) * 16 + pw) * 32 + g * 8 + sub * 4]
        = *(uint2*)zout;
  }
}

// ---------- conv2 (32->64) MFMA, B in REGS (27 frags), wave = 4 rows ----------
// grid 512 = ocg(4: 16 oc) x b(128); 256 thr = 4 waves.
__global__ __launch_bounds__(256, 2) void k_conv2(const unsigned short* __restrict__ z1bf,
    const unsigned short* __restrict__ wpk, unsigned short* __restrict__ z2bf)
{
  const int ocg = blockIdx.x & 3, b = blockIdx.x >> 2;
  const int tid = threadIdx.x;
  __shared__ __align__(16) unsigned short img[18][18][40];
  __shared__ __align__(16) unsigned short zpl[4][4][16][18];
  const int w = tid >> 6, l = tid & 63;
  const int lg = l >> 4, ll = l & 15;
  const int ry = ll >> 3, xi = ll & 7;
  bf16x8 bw[3][9];
  {
    const unsigned short* wp = wpk + ocg * 13824;
#pragma unroll
    for (int sp = 0; sp < 3; ++sp)
#pragma unroll
      for (int s9 = 0; s9 < 9; ++s9)
        bw[sp][s9] = *(const bf16x8*)(wp + ((sp * 9 + s9) * 4 + lg) * 128 + ll * 8);
  }
  int csrc[7];
#pragma unroll
  for (int k2 = 0; k2 < 7; ++k2) {
    int e = tid + k2 * 256;
    int v = -1;
    if (e < 1620) {
      int s = e / 5, u = e % 5;
      int row = s / 18, col = s % 18;
      int gy = row - 1, gx = col - 1;
      if (u < 4 && gy >= 0 && gy < 16 && gx >= 0 && gx < 16)
        v = ((b * 16 + gy) * 16 + gx) * 32 + u * 8;
    }
    csrc[k2] = v;
  }
  float vst[2][2][4], ist[2][2][4];
#pragma unroll
  for (int rp = 0; rp < 2; ++rp)
#pragma unroll
    for (int ch = 0; ch < 2; ++ch)
#pragma unroll
      for (int r = 0; r < 4; ++r) { vst[rp][ch][r] = 0.f; ist[rp][ch][r] = 0.f; }

  for (int t = 0; t < 16; ++t) {
    __syncthreads();
    {
      const unsigned short* zt = z1bf + (size_t)t * 1048576;
      uint4* imgu4 = (uint4*)&img[0][0][0];
#pragma unroll
      for (int k2 = 0; k2 < 7; ++k2) {
        int e = tid + k2 * 256;
        if (e < 1620) {
          uint4 val = {0, 0, 0, 0};
          if (csrc[k2] >= 0) val = *(const uint4*)(zt + csrc[k2]);
          imgu4[e] = val;
        }
      }
    }
    __syncthreads();
    f32x4 acc[2][2] = {};
#pragma unroll
    for (int s9 = 0; s9 < 9; ++s9) {
      const int dy = s9 / 3, dx = s9 % 3;
      bf16x8 a[2][2];
#pragma unroll
      for (int rp = 0; rp < 2; ++rp)
#pragma unroll
        for (int ch = 0; ch < 2; ++ch)
          a[rp][ch] = *(const bf16x8*)&img[4 * w + 2 * rp + ry + dy][ch * 8 + xi + dx][8 * lg];
#pragma unroll
      for (int sp = 0; sp < 3; ++sp)
#pragma unroll
        for (int rp = 0; rp < 2; ++rp)
#pragma unroll
          for (int ch = 0; ch < 2; ++ch)
            acc[rp][ch] = mfma16(a[rp][ch], bw[sp][s9], acc[rp][ch]);
    }
#pragma unroll
    for (int rp = 0; rp < 2; ++rp)
#pragma unroll
      for (int ch = 0; ch < 2; ++ch)
#pragma unroll
        for (int r = 0; r < 4; ++r) {
          int m = 4 * lg + r;
          float z = lif1(acc[rp][ch][r], 0.2f, vst[rp][ch][r], ist[rp][ch][r]);
          zpl[w][2 * rp + (m >> 3)][ch * 8 + (m & 7)][ll] = f2bf(z);
        }
#pragma unroll
    for (int pp = 0; pp < 4; ++pp) {
      int prow = lg >> 1, pcol = (lg & 1) * 4 + pp;
      float zs = bf2f(zpl[w][2*prow][2*pcol][ll])   + bf2f(zpl[w][2*prow][2*pcol+1][ll]) +
                 bf2f(zpl[w][2*prow+1][2*pcol][ll]) + bf2f(zpl[w][2*prow+1][2*pcol+1][ll]);
      z2bf[(size_t)t * 524288 + ((b * 8 + w * 2 + prow) * 8 + pcol) * 64 + ocg * 16 + ll]
          = f2bf(0.25f * zs);
    }
  }
}

// ---------- conv3 (64->128) MFMA full-K, B in REGS (54 frags) -> z3t[t] ----------
// grid 1024 = ocg(8: 16 oc) x b(128); 256 thr = 4 waves (row-pairs).
__global__ __launch_bounds__(256, 2) void k_conv3(const unsigned short* __restrict__ z2bf,
    const unsigned short* __restrict__ wpk, unsigned short* __restrict__ z3t)
{
  const int bid = blockIdx.x;
  const int ocg = bid & 7, b = bid >> 3;
  const int tid = threadIdx.x;
  __shared__ __align__(16) unsigned short img[10][12][72];
  __shared__ __align__(16) unsigned short zpl[4][16][18];
  const int w = tid >> 6, l = tid & 63;
  const int lg = l >> 4, ll = l & 15;
  const int ry = ll >> 3, xi = ll & 7;
  bf16x8 bw[2][3][9];
  {
    const unsigned short* wp = wpk + ocg * 27648;
#pragma unroll
    for (int ics = 0; ics < 2; ++ics)
#pragma unroll
      for (int sp = 0; sp < 3; ++sp)
#pragma unroll
        for (int s9 = 0; s9 < 9; ++s9)
          bw[ics][sp][s9] = *(const bf16x8*)(wp + ics * 13824 +
                                             ((sp * 9 + s9) * 4 + lg) * 128 + ll * 8);
  }
  int csrc[5];
#pragma unroll
  for (int k2 = 0; k2 < 5; ++k2) {
    int e = tid + k2 * 256;
    int v = -1;
    if (e < 1080) {
      int s = e / 9, u = e % 9;
      int row = s / 12, col = s % 12;
      int gy = row - 1, gx = col - 1;
      if (u < 8 && gy >= 0 && gy < 8 && gx >= 0 && gx < 8)
        v = ((b * 8 + gy) * 8 + gx) * 64 + u * 8;
    }
    csrc[k2] = v;
  }
  float vst[4], ist[4];
#pragma unroll
  for (int r = 0; r < 4; ++r) { vst[r] = 0.f; ist[r] = 0.f; }

  for (int t = 0; t < 16; ++t) {
    __syncthreads();
    {
      const unsigned short* zt = z2bf + (size_t)t * 524288;
      uint4* imgu4 = (uint4*)&img[0][0][0];
#pragma unroll
      for (int k2 = 0; k2 < 5; ++k2) {
        int e = tid + k2 * 256;
        if (e < 1080) {
          uint4 val = {0, 0, 0, 0};
          if (csrc[k2] >= 0) val = *(const uint4*)(zt + csrc[k2]);
          imgu4[e] = val;
        }
      }
    }
    __syncthreads();
    f32x4 acc = {};
#pragma unroll
    for (int ics = 0; ics < 2; ++ics)
#pragma unroll
      for (int s9 = 0; s9 < 9; ++s9) {
        const int dy = s9 / 3, dx = s9 % 3;
        bf16x8 a = *(const bf16x8*)&img[2 * w + ry + dy][xi + dx][ics * 32 + 8 * lg];
#pragma unroll
        for (int sp = 0; sp < 3; ++sp)
          acc = mfma16(a, bw[ics][sp][s9], acc);
      }
#pragma unroll
    for (int r = 0; r < 4; ++r) {
      int px = 4 * lg + r;
      float z = lif1(acc[r], 0.1f, vst[r], ist[r]);
      zpl[w][px][ll] = f2bf(z);
    }
    float zsum = bf2f(zpl[w][2*lg][ll])   + bf2f(zpl[w][2*lg+1][ll]) +
                 bf2f(zpl[w][8+2*lg][ll]) + bf2f(zpl[w][9+2*lg][ll]);
    z3t[(size_t)t * 262144 + b * 2048 + (ocg * 16 + ll) * 16 + w * 4 + lg]
        = f2bf(0.25f * zsum);
  }
}

// ---------- fc1 (2048->1024) MFMA, K-split 8, B in REGS (24 frags) ----------
// grid 1024 = kb8 x nb64(16 n) x bb2; 256 thr = 4 waves (bt). LDS = 32 KB slab only.
__global__ __launch_bounds__(256) void k_fc1(const unsigned short* __restrict__ z3t,
    const float* __restrict__ wf1, float* __restrict__ P1)
{
  const int bid = blockIdx.x;
  const int kb = bid & 7, nb = (bid >> 3) & 63, bb = bid >> 9;
  const int tid = threadIdx.x;
  __shared__ __align__(16) unsigned short slab[16384];  // wl3 staging first, then A-slab
  for (int i = tid; i < 4096; i += 256) {
    int n = i >> 8, k = i & 255;
    float wv = wf1[(size_t)(nb * 16 + n) * 2048 + kb * 256 + k];
    unsigned short hi = f2bf(wv);
    float r1 = wv - bf2f(hi);
    unsigned short mid = f2bf(r1);
    unsigned short lo = f2bf(r1 - bf2f(mid));
    int off = ((k >> 5) * 4 + ((k >> 3) & 3)) * 128 + n * 8 + (k & 7);
    slab[off] = hi; slab[4096 + off] = mid; slab[8192 + off] = lo;
  }
  __syncthreads();
  const int w = tid >> 6, l = tid & 63;
  const int lg = l >> 4, ll = l & 15;
  bf16x8 bwf[8][3];
#pragma unroll
  for (int ks = 0; ks < 8; ++ks)
#pragma unroll
    for (int sp = 0; sp < 3; ++sp)
      bwf[ks][sp] = *(const bf16x8*)&slab[sp * 4096 + (ks * 4 + lg) * 128 + ll * 8];
  const int arow = w * 16 + ll;
  const int bo = bb * 64 + w * 16;

  for (int t = 0; t < 16; ++t) {
    __syncthreads();                      // prior readers of slab done
    for (int gidx = tid; gidx < 2048; gidx += 256) {
      int row = gidx >> 5, gc = gidx & 31;
      const uint4* s = (const uint4*)(z3t + (size_t)t * 262144 +
                                      ((bb * 64 + row) * 2048 + kb * 256 + gc * 8));
      ((uint4*)slab)[row * 32 + (gc ^ (row & 7))] = *s;
    }
    __syncthreads();
    f32x4 acc = {};
#pragma unroll
    for (int ks = 0; ks < 8; ++ks) {
      bf16x8 a = *(const bf16x8*)&slab[(arow * 32 + ((ks * 4 + lg) ^ (arow & 7))) * 8];
#pragma unroll
      for (int sp = 0; sp < 3; ++sp)
        acc = mfma16(a, bwf[ks][sp], acc);
    }
    float* Pt = P1 + (size_t)t * 1048576 + (size_t)kb * 131072;
#pragma unroll
    for (int r = 0; r < 4; ++r)
      Pt[(bo + 4 * lg + r) * 1024 + nb * 16 + ll] = acc[r];
  }
}

// ---------- fc1 reduce + LIF(0.1), t-loop, state in regs -> z4bf[t][b][n] ----------
__global__ __launch_bounds__(256) void k_fc1b(const float* __restrict__ P1,
    unsigned short* __restrict__ z4bf)
{
  const int site = blockIdx.x * 256 + threadIdx.x;   // 131072 = b*1024+n
  float v = 0.f, ii = 0.f;
  for (int t = 0; t < 16; ++t) {
    const float* p = P1 + (size_t)t * 1048576 + site;
    float a = 0.f;
#pragma unroll
    for (int kb = 0; kb < 8; ++kb) a += p[(size_t)kb * 131072];
    float z = lif1(a, 0.1f, v, ii);
    z4bf[(size_t)t * 131072 + site] = f2bf(z);
  }
}

// ---------- out layer (1024->10) + LI + running max, t-loop, state in regs ----------
__global__ __launch_bounds__(256) void k_out(const unsigned short* __restrict__ z4bf,
    const float* __restrict__ wo, float* __restrict__ out)
{
  const int w = threadIdx.x >> 6, l = threadIdx.x & 63;
  const int b = blockIdx.x * 4 + w;
  float vo[10], io[10], om[10];
#pragma unroll
  for (int o = 0; o < 10; ++o) { vo[o] = 0.f; io[o] = 0.f; om[o] = 0.f; }
  for (int t = 0; t < 16; ++t) {
    float dot[10];
#pragma unroll
    for (int o = 0; o < 10; ++o) dot[o] = 0.f;
    for (int c = 0; c < 16; ++c) {
      const int n = c * 64 + l;
      float z = bf2f(z4bf[(size_t)t * 131072 + b * 1024 + n]);
#pragma unroll
      for (int o = 0; o < 10; ++o) dot[o] = fmaf(z, wo[o * 1024 + n], dot[o]);
    }
#pragma unroll
    for (int o = 0; o < 10; ++o)
#pragma unroll
      for (int d = 32; d > 0; d >>= 1) dot[o] += __shfl_down(dot[o], d);
    if (l == 0) {
#pragma unroll
      for (int o = 0; o < 10; ++o) {
        float vn = fmaf(0.1f, io[o] - vo[o], vo[o]);
        io[o] = fmaf(0.8f, io[o], dot[o]);
        vo[o] = vn;
        om[o] = (t == 0) ? vn : fmaxf(om[o], vn);
      }
    }
  }
  if (l == 0) {
#pragma unroll
    for (int o = 0; o < 10; ++o) out[b * 10 + o] = om[o];
  }
}

extern "C" void kernel_launch(void* const* d_in, const int* in_sizes, int n_in,
                              void* d_out, int out_size, void* d_ws, size_t ws_size,
                              hipStream_t stream)
{
  const float* x   = (const float*)d_in[0];   // (16,128,3,32,32)
  const float* wc1 = (const float*)d_in[1];   // (32,3,3,3)
  const float* wc2 = (const float*)d_in[2];   // (64,32,3,3)
  const float* wc3 = (const float*)d_in[3];   // (128,64,3,3)
  const float* wf1 = (const float*)d_in[4];   // (1024,2048)
  const float* wo  = (const float*)d_in[5];   // (10,1024)
  float* out = (float*)d_out;                 // (128,10)
  char* ws = (char*)d_ws;

  unsigned short* z1bf = (unsigned short*)(ws + 0);          // [16][128,16,16,32]
  unsigned short* z2bf = (unsigned short*)(ws + 33554432);   // [16][128,8,8,64]
  unsigned short* z3t  = (unsigned short*)(ws + 50331648);   // [16][128,2048]
  unsigned short* z4bf = (unsigned short*)(ws + 58720256);   // [16][128,1024]
  float* P1            = (float*)(ws + 62914560);            // [16][8][131072]
  unsigned short* wc2pk = (unsigned short*)(ws + 130023424);
  unsigned short* wc3pk = (unsigned short*)(ws + 130134016);

  k_pack2<<<216, 256, 0, stream>>>(wc2, wc2pk);
  k_pack3<<<1728, 256, 0, stream>>>(wc3, wc3pk);

  k_conv1<<<1024, 256, 0, stream>>>(x, wc1, z1bf);
  k_conv2<<<512, 256, 0, stream>>>(z1bf, wc2pk, z2bf);
  k_conv3<<<1024, 256, 0, stream>>>(z2bf, wc3pk, z3t);
  k_fc1 <<<1024, 256, 0, stream>>>(z3t, wf1, P1);
  k_fc1b<<<512, 256, 0, stream>>>(P1, z4bf);
  k_out <<<32, 256, 0, stream>>>(z4bf, wo, out);
}

// Round 15
// 374.580 us; speedup vs baseline: 1.5861x; 1.0367x over previous
//
#include <hip/hip_runtime.h>

// ConvSNN forward, T=16, B=128. One kernel per LAYER, t-loop inside, LIF state
// in REGISTERS. conv2/conv3/fc1 via MFMA bf16 with TRIPLE-split weights
// (hi+mid+lo ~= fp32 to ~2^-27 rel); activations are pooled spikes, exact bf16.
// B-fragments (t-invariant weights) live in REGISTERS for conv2/conv3/fc1.
// THIS ROUND: T14 async-STAGE prefetch (proven on conv1 in r14) applied to
// conv2 and conv3: staging values for t+1 are loaded into registers while t
// computes; pad regions of the LDS image written once pre-loop.

typedef __attribute__((ext_vector_type(8))) short bf16x8;
typedef __attribute__((ext_vector_type(4))) float f32x4;

__device__ __forceinline__ unsigned short f2bf(float f) {
  unsigned int u = __float_as_uint(f);
  return (unsigned short)((u + 0x7fffu + ((u >> 16) & 1u)) >> 16);
}
__device__ __forceinline__ float bf2f(unsigned short h) {
  return __uint_as_float(((unsigned int)h) << 16);
}
__device__ __forceinline__ unsigned short split3(float wv, int sp) {
  unsigned short hi = f2bf(wv);
  float r1 = wv - bf2f(hi);
  unsigned short mid = f2bf(r1);
  if (sp == 0) return hi;
  if (sp == 1) return mid;
  return f2bf(r1 - bf2f(mid));
}
__device__ __forceinline__ float lif1(float inp, float vth, float& v, float& i) {
  float vd = fmaf(0.1f, i - v, v);
  float z = (vd > vth) ? 1.0f : 0.0f;
  v = (vd > vth) ? 0.0f : vd;
  i = fmaf(0.8f, i, inp);
  return z;
}
__device__ __forceinline__ f32x4 mfma16(bf16x8 a, bf16x8 b, f32x4 c) {
  return __builtin_amdgcn_mfma_f32_16x16x32_bf16(a, b, c, 0, 0, 0);
}

// ---------- one-time weight split+pack into B-fragment order ----------
// conv2 layout: [ocg 4][sp 3][dydx 9][g 4][ocl 16][j 8]  (ic = 8g+j); 55296
__global__ __launch_bounds__(256) void k_pack2(const float* __restrict__ wc2,
                                               unsigned short* __restrict__ wpk) {
  int idx = blockIdx.x * 256 + threadIdx.x;
  if (idx >= 55296) return;
  int j = idx & 7, ocl = (idx >> 3) & 15, g = (idx >> 7) & 3;
  int r = idx >> 9;                         // 0..107
  int dydx = r % 9; int q = r / 9;          // 0..11
  int sp = q % 3, ocg = q / 3;
  int oc = ocg * 16 + ocl, ic = g * 8 + j;
  wpk[idx] = split3(wc2[(oc * 32 + ic) * 9 + dydx], sp);
}
// conv3 layout: [ocg 8][ics 2][sp 3][dydx 9][g 4][ocl 16][j 8]; 442368
__global__ __launch_bounds__(256) void k_pack3(const float* __restrict__ wc3,
                                               unsigned short* __restrict__ wpk) {
  int idx = blockIdx.x * 256 + threadIdx.x;
  if (idx >= 442368) return;
  int j = idx & 7, ocl = (idx >> 3) & 15, g = (idx >> 7) & 3;
  int r = idx >> 9;
  int dydx = r % 9; int q = r / 9;
  int sp = q % 3; int q2 = q / 3;
  int ics = q2 & 1, ocg = q2 >> 1;
  int oc = ocg * 16 + ocl, ic = ics * 32 + g * 8 + j;
  wpk[idx] = split3(wc3[(oc * 64 + ic) * 9 + dydx], sp);
}

// ---------- conv1 (3->32) fp32, t-loop, state in regs -> z1bf[t] (B,16,16,32) ----------
// grid 1024 = b(128) x h(2) x g(4: 8 oc); 256 thr; T14 prefetch (r14, proven).
__global__ __launch_bounds__(256) void k_conv1(const float* __restrict__ x,
    const float* __restrict__ wc, unsigned short* __restrict__ z1bf)
{
  const int bid = blockIdx.x;
  const int g = bid & 3, h = (bid >> 2) & 1, b = bid >> 3;
  const int tid = threadIdx.x;
  __shared__ float xs[3][18][34];
  __shared__ __align__(16) float wl[8][28];    // rows padded 27->28
  for (int i = tid; i < 216; i += 256) wl[i / 27][i % 27] = wc[g * 216 + i];
  int ssrc[8];
#pragma unroll
  for (int k2 = 0; k2 < 8; ++k2) {
    int i = tid + k2 * 256;
    int v = -1;
    if (i < 1836) {
      int c = i / 612, rr = i % 612;
      int row = rr / 34, col = rr % 34;
      int gy = h * 16 + row - 1, gx = col - 1;
      if (gy >= 0 && gy < 32 && gx >= 0 && gx < 32) v = c * 1024 + gy * 32 + gx;
    }
    ssrc[k2] = v;
  }
  const int site = tid >> 1, sub = tid & 1;
  const int ph = site >> 4, pw = site & 15;
  const int py = h * 8 + ph;
  float vst[4][4], ist[4][4];
#pragma unroll
  for (int jj = 0; jj < 4; ++jj)
#pragma unroll
    for (int r = 0; r < 4; ++r) { vst[jj][r] = 0.f; ist[jj][r] = 0.f; }

  float vals[8];
  {
    const float* xt0 = x + b * 3072;
#pragma unroll
    for (int k2 = 0; k2 < 8; ++k2)
      vals[k2] = (ssrc[k2] >= 0) ? xt0[ssrc[k2]] : 0.f;
  }

  for (int t = 0; t < 16; ++t) {
    __syncthreads();                      // prior-t readers of xs done (covers wl at t=0)
    float* xsf = &xs[0][0][0];
#pragma unroll
    for (int k2 = 0; k2 < 8; ++k2) {
      int i = tid + k2 * 256;
      if (i < 1836) xsf[i] = vals[k2];
    }
    if (t < 15) {
      const float* xt = x + (size_t)(t + 1) * 393216 + b * 3072;
#pragma unroll
      for (int k2 = 0; k2 < 8; ++k2)
        vals[k2] = (ssrc[k2] >= 0) ? xt[ssrc[k2]] : 0.f;
    }
    __syncthreads();
    float p[3][4][4];
#pragma unroll
    for (int c = 0; c < 3; ++c)
#pragma unroll
      for (int r = 0; r < 4; ++r) {
        float2 q0 = *(const float2*)&xs[c][2 * ph + r][2 * pw];
        float2 q1 = *(const float2*)&xs[c][2 * ph + r][2 * pw + 2];
        p[c][r][0] = q0.x; p[c][r][1] = q0.y; p[c][r][2] = q1.x; p[c][r][3] = q1.y;
      }
    unsigned short zout[4];
#pragma unroll
    for (int jj = 0; jj < 4; ++jj) {
      float wreg[28];
      const float4* wrow = (const float4*)&wl[sub * 4 + jj][0];
#pragma unroll
      for (int u = 0; u < 7; ++u) *(float4*)&wreg[u * 4] = wrow[u];
      float s00 = 0, s01 = 0, s10 = 0, s11 = 0;
#pragma unroll
      for (int c = 0; c < 3; ++c)
#pragma unroll
        for (int kh = 0; kh < 3; ++kh)
#pragma unroll
          for (int kw = 0; kw < 3; ++kw) {
            float wvv = wreg[(c * 3 + kh) * 3 + kw];
            s00 = fmaf(p[c][kh][kw],     wvv, s00);
            s01 = fmaf(p[c][kh][kw+1],   wvv, s01);
            s10 = fmaf(p[c][kh+1][kw],   wvv, s10);
            s11 = fmaf(p[c][kh+1][kw+1], wvv, s11);
          }
      float z0 = lif1(s00, 0.25f, vst[jj][0], ist[jj][0]);
      float z1 = lif1(s01, 0.25f, vst[jj][1], ist[jj][1]);
      float z2 = lif1(s10, 0.25f, vst[jj][2], ist[jj][2]);
      float z3 = lif1(s11, 0.25f, vst[jj][3], ist[jj][3]);
      zout[jj] = f2bf(0.25f * (z0 + z1 + z2 + z3));
    }
    *(uint2*)&z1bf[(size_t)t * 1048576 + ((b * 16 + py) * 16 + pw) * 32 + g * 8 + sub * 4]
        = *(uint2*)zout;
  }
}

// ---------- conv2 (32->64) MFMA, B in REGS (27 frags) + T14 prefetch ----------
// grid 512 = ocg(4: 16 oc) x b(128); 256 thr = 4 waves.
__global__ __launch_bounds__(256, 2) void k_conv2(const unsigned short* __restrict__ z1bf,
    const unsigned short* __restrict__ wpk, unsigned short* __restrict__ z2bf)
{
  const int ocg = blockIdx.x & 3, b = blockIdx.x >> 2;
  const int tid = threadIdx.x;
  __shared__ __align__(16) unsigned short img[18][18][40];
  __shared__ __align__(16) unsigned short zpl[4][4][16][18];
  const int w = tid >> 6, l = tid & 63;
  const int lg = l >> 4, ll = l & 15;
  const int ry = ll >> 3, xi = ll & 7;
  bf16x8 bw[3][9];
  {
    const unsigned short* wp = wpk + ocg * 13824;
#pragma unroll
    for (int sp = 0; sp < 3; ++sp)
#pragma unroll
      for (int s9 = 0; s9 < 9; ++s9)
        bw[sp][s9] = *(const bf16x8*)(wp + ((sp * 9 + s9) * 4 + lg) * 128 + ll * 8);
  }
  uint4* imgu4 = (uint4*)&img[0][0][0];
  // pad u4 (u==4 of each cell's 5) written once; data slots: 324 cells x 4 u4 = 1296
  {
    uint4 zz = {0, 0, 0, 0};
    for (int e = tid; e < 1620; e += 256)
      if ((e % 5) == 4) imgu4[e] = zz;
  }
  int csrc[6], cdst[6];
#pragma unroll
  for (int k2 = 0; k2 < 6; ++k2) {
    int e = tid + k2 * 256;
    int v = -1, d = 0;
    if (e < 1296) {
      int s = e >> 2, u = e & 3;
      int row = s / 18, col = s % 18;
      int gy = row - 1, gx = col - 1;
      d = s * 5 + u;
      if (gy >= 0 && gy < 16 && gx >= 0 && gx < 16)
        v = ((b * 16 + gy) * 16 + gx) * 32 + u * 8;
    }
    csrc[k2] = v; cdst[k2] = d;
  }
  float vst[2][2][4], ist[2][2][4];
#pragma unroll
  for (int rp = 0; rp < 2; ++rp)
#pragma unroll
    for (int ch = 0; ch < 2; ++ch)
#pragma unroll
      for (int r = 0; r < 4; ++r) { vst[rp][ch][r] = 0.f; ist[rp][ch][r] = 0.f; }

  uint4 vals[6];
  {
    const unsigned short* zt0 = z1bf;
#pragma unroll
    for (int k2 = 0; k2 < 6; ++k2) {
      uint4 val = {0, 0, 0, 0};
      if (csrc[k2] >= 0) val = *(const uint4*)(zt0 + csrc[k2]);
      vals[k2] = val;
    }
  }

  for (int t = 0; t < 16; ++t) {
    __syncthreads();                      // prior-t img readers done
#pragma unroll
    for (int k2 = 0; k2 < 6; ++k2) {
      int e = tid + k2 * 256;
      if (e < 1296) imgu4[cdst[k2]] = vals[k2];
    }
    if (t < 15) {
      const unsigned short* zt = z1bf + (size_t)(t + 1) * 1048576;
#pragma unroll
      for (int k2 = 0; k2 < 6; ++k2) {
        uint4 val = {0, 0, 0, 0};
        if (csrc[k2] >= 0) val = *(const uint4*)(zt + csrc[k2]);
        vals[k2] = val;
      }
    }
    __syncthreads();
    f32x4 acc[2][2] = {};
#pragma unroll
    for (int s9 = 0; s9 < 9; ++s9) {
      const int dy = s9 / 3, dx = s9 % 3;
      bf16x8 a[2][2];
#pragma unroll
      for (int rp = 0; rp < 2; ++rp)
#pragma unroll
        for (int ch = 0; ch < 2; ++ch)
          a[rp][ch] = *(const bf16x8*)&img[4 * w + 2 * rp + ry + dy][ch * 8 + xi + dx][8 * lg];
#pragma unroll
      for (int sp = 0; sp < 3; ++sp)
#pragma unroll
        for (int rp = 0; rp < 2; ++rp)
#pragma unroll
          for (int ch = 0; ch < 2; ++ch)
            acc[rp][ch] = mfma16(a[rp][ch], bw[sp][s9], acc[rp][ch]);
    }
#pragma unroll
    for (int rp = 0; rp < 2; ++rp)
#pragma unroll
      for (int ch = 0; ch < 2; ++ch)
#pragma unroll
        for (int r = 0; r < 4; ++r) {
          int m = 4 * lg + r;
          float z = lif1(acc[rp][ch][r], 0.2f, vst[rp][ch][r], ist[rp][ch][r]);
          zpl[w][2 * rp + (m >> 3)][ch * 8 + (m & 7)][ll] = f2bf(z);
        }
#pragma unroll
    for (int pp = 0; pp < 4; ++pp) {
      int prow = lg >> 1, pcol = (lg & 1) * 4 + pp;
      float zs = bf2f(zpl[w][2*prow][2*pcol][ll])   + bf2f(zpl[w][2*prow][2*pcol+1][ll]) +
                 bf2f(zpl[w][2*prow+1][2*pcol][ll]) + bf2f(zpl[w][2*prow+1][2*pcol+1][ll]);
      z2bf[(size_t)t * 524288 + ((b * 8 + w * 2 + prow) * 8 + pcol) * 64 + ocg * 16 + ll]
          = f2bf(0.25f * zs);
    }
  }
}

// ---------- conv3 (64->128) MFMA full-K, B in REGS (54 frags) + T14 prefetch ----------
// grid 1024 = ocg(8: 16 oc) x b(128); 256 thr = 4 waves (row-pairs).
__global__ __launch_bounds__(256, 2) void k_conv3(const unsigned short* __restrict__ z2bf,
    const unsigned short* __restrict__ wpk, unsigned short* __restrict__ z3t)
{
  const int bid = blockIdx.x;
  const int ocg = bid & 7, b = bid >> 3;
  const int tid = threadIdx.x;
  __shared__ __align__(16) unsigned short img[10][12][72];
  __shared__ __align__(16) unsigned short zpl[4][16][18];
  const int w = tid >> 6, l = tid & 63;
  const int lg = l >> 4, ll = l & 15;
  const int ry = ll >> 3, xi = ll & 7;
  bf16x8 bw[2][3][9];
  {
    const unsigned short* wp = wpk + ocg * 27648;
#pragma unroll
    for (int ics = 0; ics < 2; ++ics)
#pragma unroll
      for (int sp = 0; sp < 3; ++sp)
#pragma unroll
        for (int s9 = 0; s9 < 9; ++s9)
          bw[ics][sp][s9] = *(const bf16x8*)(wp + ics * 13824 +
                                             ((sp * 9 + s9) * 4 + lg) * 128 + ll * 8);
  }
  uint4* imgu4 = (uint4*)&img[0][0][0];
  // pad u4 (u==8 of each cell's 9) written once; data slots: 120 cells x 8 u4 = 960
  {
    uint4 zz = {0, 0, 0, 0};
    for (int e = tid; e < 1080; e += 256)
      if ((e % 9) == 8) imgu4[e] = zz;
  }
  int csrc[4], cdst[4];
#pragma unroll
  for (int k2 = 0; k2 < 4; ++k2) {
    int e = tid + k2 * 256;
    int v = -1, d = 0;
    {
      int s = e >> 3, u = e & 7;
      int row = s / 12, col = s % 12;
      int gy = row - 1, gx = col - 1;
      d = s * 9 + u;
      if (gy >= 0 && gy < 8 && gx >= 0 && gx < 8)
        v = ((b * 8 + gy) * 8 + gx) * 64 + u * 8;
    }
    csrc[k2] = v; cdst[k2] = d;
  }
  float vst[4], ist[4];
#pragma unroll
  for (int r = 0; r < 4; ++r) { vst[r] = 0.f; ist[r] = 0.f; }

  uint4 vals[4];
  {
#pragma unroll
    for (int k2 = 0; k2 < 4; ++k2) {
      uint4 val = {0, 0, 0, 0};
      if (csrc[k2] >= 0) val = *(const uint4*)(z2bf + csrc[k2]);
      vals[k2] = val;
    }
  }

  for (int t = 0; t < 16; ++t) {
    __syncthreads();                      // prior-t img/zpl readers done
#pragma unroll
    for (int k2 = 0; k2 < 4; ++k2)
      imgu4[cdst[k2]] = vals[k2];
    if (t < 15) {
      const unsigned short* zt = z2bf + (size_t)(t + 1) * 524288;
#pragma unroll
      for (int k2 = 0; k2 < 4; ++k2) {
        uint4 val = {0, 0, 0, 0};
        if (csrc[k2] >= 0) val = *(const uint4*)(zt + csrc[k2]);
        vals[k2] = val;
      }
    }
    __syncthreads();
    f32x4 acc = {};
#pragma unroll
    for (int ics = 0; ics < 2; ++ics)
#pragma unroll
      for (int s9 = 0; s9 < 9; ++s9) {
        const int dy = s9 / 3, dx = s9 % 3;
        bf16x8 a = *(const bf16x8*)&img[2 * w + ry + dy][xi + dx][ics * 32 + 8 * lg];
#pragma unroll
        for (int sp = 0; sp < 3; ++sp)
          acc = mfma16(a, bw[ics][sp][s9], acc);
      }
#pragma unroll
    for (int r = 0; r < 4; ++r) {
      int px = 4 * lg + r;
      float z = lif1(acc[r], 0.1f, vst[r], ist[r]);
      zpl[w][px][ll] = f2bf(z);
    }
    float zsum = bf2f(zpl[w][2*lg][ll])   + bf2f(zpl[w][2*lg+1][ll]) +
                 bf2f(zpl[w][8+2*lg][ll]) + bf2f(zpl[w][9+2*lg][ll]);
    z3t[(size_t)t * 262144 + b * 2048 + (ocg * 16 + ll) * 16 + w * 4 + lg]
        = f2bf(0.25f * zsum);
  }
}

// ---------- fc1 (2048->1024) MFMA, K-split 8, B in REGS (24 frags) ----------
// grid 1024 = kb8 x nb64(16 n) x bb2; 256 thr = 4 waves (bt). LDS = 32 KB slab only.
__global__ __launch_bounds__(256) void k_fc1(const unsigned short* __restrict__ z3t,
    const float* __restrict__ wf1, float* __restrict__ P1)
{
  const int bid = blockIdx.x;
  const int kb = bid & 7, nb = (bid >> 3) & 63, bb = bid >> 9;
  const int tid = threadIdx.x;
  __shared__ __align__(16) unsigned short slab[16384];  // wl3 staging first, then A-slab
  for (int i = tid; i < 4096; i += 256) {
    int n = i >> 8, k = i & 255;
    float wv = wf1[(size_t)(nb * 16 + n) * 2048 + kb * 256 + k];
    unsigned short hi = f2bf(wv);
    float r1 = wv - bf2f(hi);
    unsigned short mid = f2bf(r1);
    unsigned short lo = f2bf(r1 - bf2f(mid));
    int off = ((k >> 5) * 4 + ((k >> 3) & 3)) * 128 + n * 8 + (k & 7);
    slab[off] = hi; slab[4096 + off] = mid; slab[8192 + off] = lo;
  }
  __syncthreads();
  const int w = tid >> 6, l = tid & 63;
  const int lg = l >> 4, ll = l & 15;
  bf16x8 bwf[8][3];
#pragma unroll
  for (int ks = 0; ks < 8; ++ks)
#pragma unroll
    for (int sp = 0; sp < 3; ++sp)
      bwf[ks][sp] = *(const bf16x8*)&slab[sp * 4096 + (ks * 4 + lg) * 128 + ll * 8];
  const int arow = w * 16 + ll;
  const int bo = bb * 64 + w * 16;

  for (int t = 0; t < 16; ++t) {
    __syncthreads();                      // prior readers of slab done
    for (int gidx = tid; gidx < 2048; gidx += 256) {
      int row = gidx >> 5, gc = gidx & 31;
      const uint4* s = (const uint4*)(z3t + (size_t)t * 262144 +
                                      ((bb * 64 + row) * 2048 + kb * 256 + gc * 8));
      ((uint4*)slab)[row * 32 + (gc ^ (row & 7))] = *s;
    }
    __syncthreads();
    f32x4 acc = {};
#pragma unroll
    for (int ks = 0; ks < 8; ++ks) {
      bf16x8 a = *(const bf16x8*)&slab[(arow * 32 + ((ks * 4 + lg) ^ (arow & 7))) * 8];
#pragma unroll
      for (int sp = 0; sp < 3; ++sp)
        acc = mfma16(a, bwf[ks][sp], acc);
    }
    float* Pt = P1 + (size_t)t * 1048576 + (size_t)kb * 131072;
#pragma unroll
    for (int r = 0; r < 4; ++r)
      Pt[(bo + 4 * lg + r) * 1024 + nb * 16 + ll] = acc[r];
  }
}

// ---------- fc1 reduce + LIF(0.1), t-loop, state in regs -> z4bf[t][b][n] ----------
__global__ __launch_bounds__(256) void k_fc1b(const float* __restrict__ P1,
    unsigned short* __restrict__ z4bf)
{
  const int site = blockIdx.x * 256 + threadIdx.x;   // 131072 = b*1024+n
  float v = 0.f, ii = 0.f;
  for (int t = 0; t < 16; ++t) {
    const float* p = P1 + (size_t)t * 1048576 + site;
    float a = 0.f;
#pragma unroll
    for (int kb = 0; kb < 8; ++kb) a += p[(size_t)kb * 131072];
    float z = lif1(a, 0.1f, v, ii);
    z4bf[(size_t)t * 131072 + site] = f2bf(z);
  }
}

// ---------- out layer (1024->10) + LI + running max, t-loop, state in regs ----------
__global__ __launch_bounds__(256) void k_out(const unsigned short* __restrict__ z4bf,
    const float* __restrict__ wo, float* __restrict__ out)
{
  const int w = threadIdx.x >> 6, l = threadIdx.x & 63;
  const int b = blockIdx.x * 4 + w;
  float vo[10], io[10], om[10];
#pragma unroll
  for (int o = 0; o < 10; ++o) { vo[o] = 0.f; io[o] = 0.f; om[o] = 0.f; }
  for (int t = 0; t < 16; ++t) {
    float dot[10];
#pragma unroll
    for (int o = 0; o < 10; ++o) dot[o] = 0.f;
    for (int c = 0; c < 16; ++c) {
      const int n = c * 64 + l;
      float z = bf2f(z4bf[(size_t)t * 131072 + b * 1024 + n]);
#pragma unroll
      for (int o = 0; o < 10; ++o) dot[o] = fmaf(z, wo[o * 1024 + n], dot[o]);
    }
#pragma unroll
    for (int o = 0; o < 10; ++o)
#pragma unroll
      for (int d = 32; d > 0; d >>= 1) dot[o] += __shfl_down(dot[o], d);
    if (l == 0) {
#pragma unroll
      for (int o = 0; o < 10; ++o) {
        float vn = fmaf(0.1f, io[o] - vo[o], vo[o]);
        io[o] = fmaf(0.8f, io[o], dot[o]);
        vo[o] = vn;
        om[o] = (t == 0) ? vn : fmaxf(om[o], vn);
      }
    }
  }
  if (l == 0) {
#pragma unroll
    for (int o = 0; o < 10; ++o) out[b * 10 + o] = om[o];
  }
}

extern "C" void kernel_launch(void* const* d_in, const int* in_sizes, int n_in,
                              void* d_out, int out_size, void* d_ws, size_t ws_size,
                              hipStream_t stream)
{
  const float* x   = (const float*)d_in[0];   // (16,128,3,32,32)
  const float* wc1 = (const float*)d_in[1];   // (32,3,3,3)
  const float* wc2 = (const float*)d_in[2];   // (64,32,3,3)
  const float* wc3 = (const float*)d_in[3];   // (128,64,3,3)
  const float* wf1 = (const float*)d_in[4];   // (1024,2048)
  const float* wo  = (const float*)d_in[5];   // (10,1024)
  float* out = (float*)d_out;                 // (128,10)
  char* ws = (char*)d_ws;

  unsigned short* z1bf = (unsigned short*)(ws + 0);          // [16][128,16,16,32]
  unsigned short* z2bf = (unsigned short*)(ws + 33554432);   // [16][128,8,8,64]
  unsigned short* z3t  = (unsigned short*)(ws + 50331648);   // [16][128,2048]
  unsigned short* z4bf = (unsigned short*)(ws + 58720256);   // [16][128,1024]
  float* P1            = (float*)(ws + 62914560);            // [16][8][131072]
  unsigned short* wc2pk = (unsigned short*)(ws + 130023424);
  unsigned short* wc3pk = (unsigned short*)(ws + 130134016);

  k_pack2<<<216, 256, 0, stream>>>(wc2, wc2pk);
  k_pack3<<<1728, 256, 0, stream>>>(wc3, wc3pk);

  k_conv1<<<1024, 256, 0, stream>>>(x, wc1, z1bf);
  k_conv2<<<512, 256, 0, stream>>>(z1bf, wc2pk, z2bf);
  k_conv3<<<1024, 256, 0, stream>>>(z2bf, wc3pk, z3t);
  k_fc1 <<<1024, 256, 0, stream>>>(z3t, wf1, P1);
  k_fc1b<<<512, 256, 0, stream>>>(P1, z4bf);
  k_out <<<32, 256, 0, stream>>>(z4bf, wo, out);
}

// Round 16
// 369.929 us; speedup vs baseline: 1.6061x; 1.0126x over previous
//
#include <hip/hip_runtime.h>

// ConvSNN forward, T=16, B=128. One kernel per LAYER, t-loop inside, LIF state
// in REGISTERS. conv2/conv3/fc1 via MFMA bf16 with TRIPLE-split weights
// (hi+mid+lo ~= fp32 to ~2^-27 rel); activations are pooled spikes, exact bf16.
// B-fragments (t-invariant weights) in REGISTERS for conv2/conv3/fc1.
// THIS ROUND: LDS DOUBLE-BUFFER in conv1/conv2/conv3 -> ONE barrier per t;
// ds_writes of t+1 and global prefetch of t+2 overlap compute of t.

typedef __attribute__((ext_vector_type(8))) short bf16x8;
typedef __attribute__((ext_vector_type(4))) float f32x4;

__device__ __forceinline__ unsigned short f2bf(float f) {
  unsigned int u = __float_as_uint(f);
  return (unsigned short)((u + 0x7fffu + ((u >> 16) & 1u)) >> 16);
}
__device__ __forceinline__ float bf2f(unsigned short h) {
  return __uint_as_float(((unsigned int)h) << 16);
}
__device__ __forceinline__ unsigned short split3(float wv, int sp) {
  unsigned short hi = f2bf(wv);
  float r1 = wv - bf2f(hi);
  unsigned short mid = f2bf(r1);
  if (sp == 0) return hi;
  if (sp == 1) return mid;
  return f2bf(r1 - bf2f(mid));
}
__device__ __forceinline__ float lif1(float inp, float vth, float& v, float& i) {
  float vd = fmaf(0.1f, i - v, v);
  float z = (vd > vth) ? 1.0f : 0.0f;
  v = (vd > vth) ? 0.0f : vd;
  i = fmaf(0.8f, i, inp);
  return z;
}
__device__ __forceinline__ f32x4 mfma16(bf16x8 a, bf16x8 b, f32x4 c) {
  return __builtin_amdgcn_mfma_f32_16x16x32_bf16(a, b, c, 0, 0, 0);
}

// ---------- one-time weight split+pack into B-fragment order ----------
// conv2 layout: [ocg 4][sp 3][dydx 9][g 4][ocl 16][j 8]  (ic = 8g+j); 55296
__global__ __launch_bounds__(256) void k_pack2(const float* __restrict__ wc2,
                                               unsigned short* __restrict__ wpk) {
  int idx = blockIdx.x * 256 + threadIdx.x;
  if (idx >= 55296) return;
  int j = idx & 7, ocl = (idx >> 3) & 15, g = (idx >> 7) & 3;
  int r = idx >> 9;                         // 0..107
  int dydx = r % 9; int q = r / 9;          // 0..11
  int sp = q % 3, ocg = q / 3;
  int oc = ocg * 16 + ocl, ic = g * 8 + j;
  wpk[idx] = split3(wc2[(oc * 32 + ic) * 9 + dydx], sp);
}
// conv3 layout: [ocg 8][ics 2][sp 3][dydx 9][g 4][ocl 16][j 8]; 442368
__global__ __launch_bounds__(256) void k_pack3(const float* __restrict__ wc3,
                                               unsigned short* __restrict__ wpk) {
  int idx = blockIdx.x * 256 + threadIdx.x;
  if (idx >= 442368) return;
  int j = idx & 7, ocl = (idx >> 3) & 15, g = (idx >> 7) & 3;
  int r = idx >> 9;
  int dydx = r % 9; int q = r / 9;
  int sp = q % 3; int q2 = q / 3;
  int ics = q2 & 1, ocg = q2 >> 1;
  int oc = ocg * 16 + ocl, ic = ics * 32 + g * 8 + j;
  wpk[idx] = split3(wc3[(oc * 64 + ic) * 9 + dydx], sp);
}

// ---------- conv1 (3->32) fp32, double-buffered LDS, 1 barrier/t ----------
// grid 1024 = b(128) x h(2) x g(4: 8 oc); 256 thr = 128 sites x 2 sub(4 oc each).
__global__ __launch_bounds__(256) void k_conv1(const float* __restrict__ x,
    const float* __restrict__ wc, unsigned short* __restrict__ z1bf)
{
  const int bid = blockIdx.x;
  const int g = bid & 3, h = (bid >> 2) & 1, b = bid >> 3;
  const int tid = threadIdx.x;
  __shared__ float xs[2][3][18][34];           // 2 x 7344 B
  __shared__ __align__(16) float wl[8][28];    // rows padded 27->28
  for (int i = tid; i < 216; i += 256) wl[i / 27][i % 27] = wc[g * 216 + i];
  int ssrc[8];
#pragma unroll
  for (int k2 = 0; k2 < 8; ++k2) {
    int i = tid + k2 * 256;
    int v = -1;
    if (i < 1836) {
      int c = i / 612, rr = i % 612;
      int row = rr / 34, col = rr % 34;
      int gy = h * 16 + row - 1, gx = col - 1;
      if (gy >= 0 && gy < 32 && gx >= 0 && gx < 32) v = c * 1024 + gy * 32 + gx;
    }
    ssrc[k2] = v;
  }
  const int site = tid >> 1, sub = tid & 1;
  const int ph = site >> 4, pw = site & 15;
  const int py = h * 8 + ph;
  float vst[4][4], ist[4][4];
#pragma unroll
  for (int jj = 0; jj < 4; ++jj)
#pragma unroll
    for (int r = 0; r < 4; ++r) { vst[jj][r] = 0.f; ist[jj][r] = 0.f; }

  float vals[8];
  float* xsf0 = &xs[0][0][0][0];
  float* xsf1 = &xs[1][0][0][0];
  {
    const float* xt0 = x + b * 3072;
#pragma unroll
    for (int k2 = 0; k2 < 8; ++k2)
      vals[k2] = (ssrc[k2] >= 0) ? xt0[ssrc[k2]] : 0.f;
#pragma unroll
    for (int k2 = 0; k2 < 8; ++k2) {
      int i = tid + k2 * 256;
      if (i < 1836) xsf0[i] = vals[k2];
    }
    const float* xt1 = x + 393216 + b * 3072;
#pragma unroll
    for (int k2 = 0; k2 < 8; ++k2)
      vals[k2] = (ssrc[k2] >= 0) ? xt1[ssrc[k2]] : 0.f;
  }
  __syncthreads();                             // wl + buf0 staged

  for (int t = 0; t < 16; ++t) {
    float* xw = (t & 1) ? xsf0 : xsf1;         // write target = buf[(t+1)&1]
    const float (*xr)[18][34] = xs[t & 1];     // read buffer
    if (t < 15) {
#pragma unroll
      for (int k2 = 0; k2 < 8; ++k2) {
        int i = tid + k2 * 256;
        if (i < 1836) xw[i] = vals[k2];
      }
    }
    if (t < 14) {
      const float* xt = x + (size_t)(t + 2) * 393216 + b * 3072;
#pragma unroll
      for (int k2 = 0; k2 < 8; ++k2)
        vals[k2] = (ssrc[k2] >= 0) ? xt[ssrc[k2]] : 0.f;
    }
    float p[3][4][4];
#pragma unroll
    for (int c = 0; c < 3; ++c)
#pragma unroll
      for (int r = 0; r < 4; ++r) {
        float2 q0 = *(const float2*)&xr[c][2 * ph + r][2 * pw];
        float2 q1 = *(const float2*)&xr[c][2 * ph + r][2 * pw + 2];
        p[c][r][0] = q0.x; p[c][r][1] = q0.y; p[c][r][2] = q1.x; p[c][r][3] = q1.y;
      }
    unsigned short zout[4];
#pragma unroll
    for (int jj = 0; jj < 4; ++jj) {
      float wreg[28];
      const float4* wrow = (const float4*)&wl[sub * 4 + jj][0];
#pragma unroll
      for (int u = 0; u < 7; ++u) *(float4*)&wreg[u * 4] = wrow[u];
      float s00 = 0, s01 = 0, s10 = 0, s11 = 0;
#pragma unroll
      for (int c = 0; c < 3; ++c)
#pragma unroll
        for (int kh = 0; kh < 3; ++kh)
#pragma unroll
          for (int kw = 0; kw < 3; ++kw) {
            float wvv = wreg[(c * 3 + kh) * 3 + kw];
            s00 = fmaf(p[c][kh][kw],     wvv, s00);
            s01 = fmaf(p[c][kh][kw+1],   wvv, s01);
            s10 = fmaf(p[c][kh+1][kw],   wvv, s10);
            s11 = fmaf(p[c][kh+1][kw+1], wvv, s11);
          }
      float z0 = lif1(s00, 0.25f, vst[jj][0], ist[jj][0]);
      float z1 = lif1(s01, 0.25f, vst[jj][1], ist[jj][1]);
      float z2 = lif1(s10, 0.25f, vst[jj][2], ist[jj][2]);
      float z3 = lif1(s11, 0.25f, vst[jj][3], ist[jj][3]);
      zout[jj] = f2bf(0.25f * (z0 + z1 + z2 + z3));
    }
    *(uint2*)&z1bf[(size_t)t * 1048576 + ((b * 16 + py) * 16 + pw) * 32 + g * 8 + sub * 4]
        = *(uint2*)zout;
    __syncthreads();                           // single barrier per t
  }
}

// ---------- conv2 (32->64) MFMA, B in REGS, double-buffered img, 1 barrier/t ----------
// grid 512 = ocg(4: 16 oc) x b(128); 256 thr = 4 waves.
__global__ __launch_bounds__(256, 2) void k_conv2(const unsigned short* __restrict__ z1bf,
    const unsigned short* __restrict__ wpk, unsigned short* __restrict__ z2bf)
{
  const int ocg = blockIdx.x & 3, b = blockIdx.x >> 2;
  const int tid = threadIdx.x;
  __shared__ __align__(16) unsigned short img[2][18][18][40];   // 2 x 25920 B
  __shared__ __align__(16) unsigned short zpl[4][4][16][18];
  const int w = tid >> 6, l = tid & 63;
  const int lg = l >> 4, ll = l & 15;
  const int ry = ll >> 3, xi = ll & 7;
  bf16x8 bw[3][9];
  {
    const unsigned short* wp = wpk + ocg * 13824;
#pragma unroll
    for (int sp = 0; sp < 3; ++sp)
#pragma unroll
      for (int s9 = 0; s9 < 9; ++s9)
        bw[sp][s9] = *(const bf16x8*)(wp + ((sp * 9 + s9) * 4 + lg) * 128 + ll * 8);
  }
  uint4* imgu4 = (uint4*)&img[0][0][0][0];
  {
    uint4 zz = {0, 0, 0, 0};
    for (int e = tid; e < 1620; e += 256)
      if ((e % 5) == 4) { imgu4[e] = zz; imgu4[1620 + e] = zz; }
  }
  int csrc[6], cdst[6];
#pragma unroll
  for (int k2 = 0; k2 < 6; ++k2) {
    int e = tid + k2 * 256;
    int v = -1, d = 0;
    if (e < 1296) {
      int s = e >> 2, u = e & 3;
      int row = s / 18, col = s % 18;
      int gy = row - 1, gx = col - 1;
      d = s * 5 + u;
      if (gy >= 0 && gy < 16 && gx >= 0 && gx < 16)
        v = ((b * 16 + gy) * 16 + gx) * 32 + u * 8;
    }
    csrc[k2] = v; cdst[k2] = d;
  }
  float vst[2][2][4], ist[2][2][4];
#pragma unroll
  for (int rp = 0; rp < 2; ++rp)
#pragma unroll
    for (int ch = 0; ch < 2; ++ch)
#pragma unroll
      for (int r = 0; r < 4; ++r) { vst[rp][ch][r] = 0.f; ist[rp][ch][r] = 0.f; }

  uint4 vals[6];
  {
#pragma unroll
    for (int k2 = 0; k2 < 6; ++k2) {
      uint4 val = {0, 0, 0, 0};
      if (csrc[k2] >= 0) val = *(const uint4*)(z1bf + csrc[k2]);
      vals[k2] = val;
    }
#pragma unroll
    for (int k2 = 0; k2 < 6; ++k2) {
      int e = tid + k2 * 256;
      if (e < 1296) imgu4[cdst[k2]] = vals[k2];
    }
    const unsigned short* zt1 = z1bf + 1048576;
#pragma unroll
    for (int k2 = 0; k2 < 6; ++k2) {
      uint4 val = {0, 0, 0, 0};
      if (csrc[k2] >= 0) val = *(const uint4*)(zt1 + csrc[k2]);
      vals[k2] = val;
    }
  }
  __syncthreads();                             // buf0 staged

  for (int t = 0; t < 16; ++t) {
    const int cur = t & 1, nxt = cur ^ 1;
    if (t < 15) {
#pragma unroll
      for (int k2 = 0; k2 < 6; ++k2) {
        int e = tid + k2 * 256;
        if (e < 1296) imgu4[nxt * 1620 + cdst[k2]] = vals[k2];
      }
    }
    if (t < 14) {
      const unsigned short* zt = z1bf + (size_t)(t + 2) * 1048576;
#pragma unroll
      for (int k2 = 0; k2 < 6; ++k2) {
        uint4 val = {0, 0, 0, 0};
        if (csrc[k2] >= 0) val = *(const uint4*)(zt + csrc[k2]);
        vals[k2] = val;
      }
    }
    f32x4 acc[2][2] = {};
#pragma unroll
    for (int s9 = 0; s9 < 9; ++s9) {
      const int dy = s9 / 3, dx = s9 % 3;
      bf16x8 a[2][2];
#pragma unroll
      for (int rp = 0; rp < 2; ++rp)
#pragma unroll
        for (int ch = 0; ch < 2; ++ch)
          a[rp][ch] = *(const bf16x8*)&img[cur][4 * w + 2 * rp + ry + dy][ch * 8 + xi + dx][8 * lg];
#pragma unroll
      for (int sp = 0; sp < 3; ++sp)
#pragma unroll
        for (int rp = 0; rp < 2; ++rp)
#pragma unroll
          for (int ch = 0; ch < 2; ++ch)
            acc[rp][ch] = mfma16(a[rp][ch], bw[sp][s9], acc[rp][ch]);
    }
#pragma unroll
    for (int rp = 0; rp < 2; ++rp)
#pragma unroll
      for (int ch = 0; ch < 2; ++ch)
#pragma unroll
        for (int r = 0; r < 4; ++r) {
          int m = 4 * lg + r;
          float z = lif1(acc[rp][ch][r], 0.2f, vst[rp][ch][r], ist[rp][ch][r]);
          zpl[w][2 * rp + (m >> 3)][ch * 8 + (m & 7)][ll] = f2bf(z);
        }
#pragma unroll
    for (int pp = 0; pp < 4; ++pp) {
      int prow = lg >> 1, pcol = (lg & 1) * 4 + pp;
      float zs = bf2f(zpl[w][2*prow][2*pcol][ll])   + bf2f(zpl[w][2*prow][2*pcol+1][ll]) +
                 bf2f(zpl[w][2*prow+1][2*pcol][ll]) + bf2f(zpl[w][2*prow+1][2*pcol+1][ll]);
      z2bf[(size_t)t * 524288 + ((b * 8 + w * 2 + prow) * 8 + pcol) * 64 + ocg * 16 + ll]
          = f2bf(0.25f * zs);
    }
    __syncthreads();                           // single barrier per t
  }
}

// ---------- conv3 (64->128) MFMA full-K, B in REGS, double-buffered img, 1 barrier/t ----------
// grid 1024 = ocg(8: 16 oc) x b(128); 256 thr = 4 waves (row-pairs).
__global__ __launch_bounds__(256, 2) void k_conv3(const unsigned short* __restrict__ z2bf,
    const unsigned short* __restrict__ wpk, unsigned short* __restrict__ z3t)
{
  const int bid = blockIdx.x;
  const int ocg = bid & 7, b = bid >> 3;
  const int tid = threadIdx.x;
  __shared__ __align__(16) unsigned short img[2][10][12][72];   // 2 x 17280 B
  __shared__ __align__(16) unsigned short zpl[4][16][18];
  const int w = tid >> 6, l = tid & 63;
  const int lg = l >> 4, ll = l & 15;
  const int ry = ll >> 3, xi = ll & 7;
  bf16x8 bw[2][3][9];
  {
    const unsigned short* wp = wpk + ocg * 27648;
#pragma unroll
    for (int ics = 0; ics < 2; ++ics)
#pragma unroll
      for (int sp = 0; sp < 3; ++sp)
#pragma unroll
        for (int s9 = 0; s9 < 9; ++s9)
          bw[ics][sp][s9] = *(const bf16x8*)(wp + ics * 13824 +
                                             ((sp * 9 + s9) * 4 + lg) * 128 + ll * 8);
  }
  uint4* imgu4 = (uint4*)&img[0][0][0][0];
  {
    uint4 zz = {0, 0, 0, 0};
    for (int e = tid; e < 1080; e += 256)
      if ((e % 9) == 8) { imgu4[e] = zz; imgu4[1080 + e] = zz; }
  }
  int csrc[4], cdst[4];
#pragma unroll
  for (int k2 = 0; k2 < 4; ++k2) {
    int e = tid + k2 * 256;
    int v = -1, d = 0;
    {
      int s = e >> 3, u = e & 7;
      int row = s / 12, col = s % 12;
      int gy = row - 1, gx = col - 1;
      d = s * 9 + u;
      if (gy >= 0 && gy < 8 && gx >= 0 && gx < 8)
        v = ((b * 8 + gy) * 8 + gx) * 64 + u * 8;
    }
    csrc[k2] = v; cdst[k2] = d;
  }
  float vst[4], ist[4];
#pragma unroll
  for (int r = 0; r < 4; ++r) { vst[r] = 0.f; ist[r] = 0.f; }

  uint4 vals[4];
  {
#pragma unroll
    for (int k2 = 0; k2 < 4; ++k2) {
      uint4 val = {0, 0, 0, 0};
      if (csrc[k2] >= 0) val = *(const uint4*)(z2bf + csrc[k2]);
      vals[k2] = val;
    }
#pragma unroll
    for (int k2 = 0; k2 < 4; ++k2)
      imgu4[cdst[k2]] = vals[k2];
    const unsigned short* zt1 = z2bf + 524288;
#pragma unroll
    for (int k2 = 0; k2 < 4; ++k2) {
      uint4 val = {0, 0, 0, 0};
      if (csrc[k2] >= 0) val = *(const uint4*)(zt1 + csrc[k2]);
      vals[k2] = val;
    }
  }
  __syncthreads();                             // buf0 staged

  for (int t = 0; t < 16; ++t) {
    const int cur = t & 1, nxt = cur ^ 1;
    if (t < 15) {
#pragma unroll
      for (int k2 = 0; k2 < 4; ++k2)
        imgu4[nxt * 1080 + cdst[k2]] = vals[k2];
    }
    if (t < 14) {
      const unsigned short* zt = z2bf + (size_t)(t + 2) * 524288;
#pragma unroll
      for (int k2 = 0; k2 < 4; ++k2) {
        uint4 val = {0, 0, 0, 0};
        if (csrc[k2] >= 0) val = *(const uint4*)(zt + csrc[k2]);
        vals[k2] = val;
      }
    }
    f32x4 acc = {};
#pragma unroll
    for (int ics = 0; ics < 2; ++ics)
#pragma unroll
      for (int s9 = 0; s9 < 9; ++s9) {
        const int dy = s9 / 3, dx = s9 % 3;
        bf16x8 a = *(const bf16x8*)&img[cur][2 * w + ry + dy][xi + dx][ics * 32 + 8 * lg];
#pragma unroll
        for (int sp = 0; sp < 3; ++sp)
          acc = mfma16(a, bw[ics][sp][s9], acc);
      }
#pragma unroll
    for (int r = 0; r < 4; ++r) {
      int px = 4 * lg + r;
      float z = lif1(acc[r], 0.1f, vst[r], ist[r]);
      zpl[w][px][ll] = f2bf(z);
    }
    float zsum = bf2f(zpl[w][2*lg][ll])   + bf2f(zpl[w][2*lg+1][ll]) +
                 bf2f(zpl[w][8+2*lg][ll]) + bf2f(zpl[w][9+2*lg][ll]);
    z3t[(size_t)t * 262144 + b * 2048 + (ocg * 16 + ll) * 16 + w * 4 + lg]
        = f2bf(0.25f * zsum);
    __syncthreads();                           // single barrier per t
  }
}

// ---------- fc1 (2048->1024) MFMA, K-split 8, B in REGS (24 frags) ----------
// grid 1024 = kb8 x nb64(16 n) x bb2; 256 thr = 4 waves (bt). LDS = 32 KB slab only.
__global__ __launch_bounds__(256) void k_fc1(const unsigned short* __restrict__ z3t,
    const float* __restrict__ wf1, float* __restrict__ P1)
{
  const int bid = blockIdx.x;
  const int kb = bid & 7, nb = (bid >> 3) & 63, bb = bid >> 9;
  const int tid = threadIdx.x;
  __shared__ __align__(16) unsigned short slab[16384];  // wl3 staging first, then A-slab
  for (int i = tid; i < 4096; i += 256) {
    int n = i >> 8, k = i & 255;
    float wv = wf1[(size_t)(nb * 16 + n) * 2048 + kb * 256 + k];
    unsigned short hi = f2bf(wv);
    float r1 = wv - bf2f(hi);
    unsigned short mid = f2bf(r1);
    unsigned short lo = f2bf(r1 - bf2f(mid));
    int off = ((k >> 5) * 4 + ((k >> 3) & 3)) * 128 + n * 8 + (k & 7);
    slab[off] = hi; slab[4096 + off] = mid; slab[8192 + off] = lo;
  }
  __syncthreads();
  const int w = tid >> 6, l = tid & 63;
  const int lg = l >> 4, ll = l & 15;
  bf16x8 bwf[8][3];
#pragma unroll
  for (int ks = 0; ks < 8; ++ks)
#pragma unroll
    for (int sp = 0; sp < 3; ++sp)
      bwf[ks][sp] = *(const bf16x8*)&slab[sp * 4096 + (ks * 4 + lg) * 128 + ll * 8];
  const int arow = w * 16 + ll;
  const int bo = bb * 64 + w * 16;

  for (int t = 0; t < 16; ++t) {
    __syncthreads();                      // prior readers of slab done
    for (int gidx = tid; gidx < 2048; gidx += 256) {
      int row = gidx >> 5, gc = gidx & 31;
      const uint4* s = (const uint4*)(z3t + (size_t)t * 262144 +
                                      ((bb * 64 + row) * 2048 + kb * 256 + gc * 8));
      ((uint4*)slab)[row * 32 + (gc ^ (row & 7))] = *s;
    }
    __syncthreads();
    f32x4 acc = {};
#pragma unroll
    for (int ks = 0; ks < 8; ++ks) {
      bf16x8 a = *(const bf16x8*)&slab[(arow * 32 + ((ks * 4 + lg) ^ (arow & 7))) * 8];
#pragma unroll
      for (int sp = 0; sp < 3; ++sp)
        acc = mfma16(a, bwf[ks][sp], acc);
    }
    float* Pt = P1 + (size_t)t * 1048576 + (size_t)kb * 131072;
#pragma unroll
    for (int r = 0; r < 4; ++r)
      Pt[(bo + 4 * lg + r) * 1024 + nb * 16 + ll] = acc[r];
  }
}

// ---------- fc1 reduce + LIF(0.1), t-loop, state in regs -> z4bf[t][b][n] ----------
__global__ __launch_bounds__(256) void k_fc1b(const float* __restrict__ P1,
    unsigned short* __restrict__ z4bf)
{
  const int site = blockIdx.x * 256 + threadIdx.x;   // 131072 = b*1024+n
  float v = 0.f, ii = 0.f;
  for (int t = 0; t < 16; ++t) {
    const float* p = P1 + (size_t)t * 1048576 + site;
    float a = 0.f;
#pragma unroll
    for (int kb = 0; kb < 8; ++kb) a += p[(size_t)kb * 131072];
    float z = lif1(a, 0.1f, v, ii);
    z4bf[(size_t)t * 131072 + site] = f2bf(z);
  }
}

// ---------- out layer (1024->10) + LI + running max, t-loop, state in regs ----------
__global__ __launch_bounds__(256) void k_out(const unsigned short* __restrict__ z4bf,
    const float* __restrict__ wo, float* __restrict__ out)
{
  const int w = threadIdx.x >> 6, l = threadIdx.x & 63;
  const int b = blockIdx.x * 4 + w;
  float vo[10], io[10], om[10];
#pragma unroll
  for (int o = 0; o < 10; ++o) { vo[o] = 0.f; io[o] = 0.f; om[o] = 0.f; }
  for (int t = 0; t < 16; ++t) {
    float dot[10];
#pragma unroll
    for (int o = 0; o < 10; ++o) dot[o] = 0.f;
    for (int c = 0; c < 16; ++c) {
      const int n = c * 64 + l;
      float z = bf2f(z4bf[(size_t)t * 131072 + b * 1024 + n]);
#pragma unroll
      for (int o = 0; o < 10; ++o) dot[o] = fmaf(z, wo[o * 1024 + n], dot[o]);
    }
#pragma unroll
    for (int o = 0; o < 10; ++o)
#pragma unroll
      for (int d = 32; d > 0; d >>= 1) dot[o] += __shfl_down(dot[o], d);
    if (l == 0) {
#pragma unroll
      for (int o = 0; o < 10; ++o) {
        float vn = fmaf(0.1f, io[o] - vo[o], vo[o]);
        io[o] = fmaf(0.8f, io[o], dot[o]);
        vo[o] = vn;
        om[o] = (t == 0) ? vn : fmaxf(om[o], vn);
      }
    }
  }
  if (l == 0) {
#pragma unroll
    for (int o = 0; o < 10; ++o) out[b * 10 + o] = om[o];
  }
}

extern "C" void kernel_launch(void* const* d_in, const int* in_sizes, int n_in,
                              void* d_out, int out_size, void* d_ws, size_t ws_size,
                              hipStream_t stream)
{
  const float* x   = (const float*)d_in[0];   // (16,128,3,32,32)
  const float* wc1 = (const float*)d_in[1];   // (32,3,3,3)
  const float* wc2 = (const float*)d_in[2];   // (64,32,3,3)
  const float* wc3 = (const float*)d_in[3];   // (128,64,3,3)
  const float* wf1 = (const float*)d_in[4];   // (1024,2048)
  const float* wo  = (const float*)d_in[5];   // (10,1024)
  float* out = (float*)d_out;                 // (128,10)
  char* ws = (char*)d_ws;

  unsigned short* z1bf = (unsigned short*)(ws + 0);          // [16][128,16,16,32]
  unsigned short* z2bf = (unsigned short*)(ws + 33554432);   // [16][128,8,8,64]
  unsigned short* z3t  = (unsigned short*)(ws + 50331648);   // [16][128,2048]
  unsigned short* z4bf = (unsigned short*)(ws + 58720256);   // [16][128,1024]
  float* P1            = (float*)(ws + 62914560);            // [16][8][131072]
  unsigned short* wc2pk = (unsigned short*)(ws + 130023424);
  unsigned short* wc3pk = (unsigned short*)(ws + 130134016);

  k_pack2<<<216, 256, 0, stream>>>(wc2, wc2pk);
  k_pack3<<<1728, 256, 0, stream>>>(wc3, wc3pk);

  k_conv1<<<1024, 256, 0, stream>>>(x, wc1, z1bf);
  k_conv2<<<512, 256, 0, stream>>>(z1bf, wc2pk, z2bf);
  k_conv3<<<1024, 256, 0, stream>>>(z2bf, wc3pk, z3t);
  k_fc1 <<<1024, 256, 0, stream>>>(z3t, wf1, P1);
  k_fc1b<<<512, 256, 0, stream>>>(P1, z4bf);
  k_out <<<32, 256, 0, stream>>>(z4bf, wo, out);
}